// Round 3
// baseline (1991.507 us; speedup 1.0000x reference)
//
#include <hip/hip_runtime.h>
#include <hip/hip_bf16.h>

typedef unsigned short u16;
typedef unsigned int   u32;
typedef unsigned long long u64;
typedef __attribute__((ext_vector_type(8))) short bf16x8;
typedef __attribute__((ext_vector_type(4))) float f32x4;

#define MFMA16(a,b,c) __builtin_amdgcn_mfma_f32_16x16x32_bf16(a,b,c,0,0,0)

// ---- problem dims ----
#define NV_   321
#define B_    16
#define L_    512
#define D_    128
#define P_    64
#define E_    8
#define H_    512
#define NRW   5136        // B*NV
#define NTOK  328704      // NRW*P
#define DP_   8192        // D*P
#define NBUCK 329728      // NTOK + 8*128 padding

static __device__ __forceinline__ u16 f2bf(float f){
  __hip_bfloat16 h = __float2bfloat16(f);
  return *reinterpret_cast<u16*>(&h);
}

static __device__ __forceinline__ float gelu_f(float x){
  return 0.5f*x*(1.0f + erff(0.70710678118654752f*x));   // exact erf form
}

static __device__ __forceinline__ u32 bfadd2(u32 a, u32 b){
  float lo = __uint_as_float(a<<16)           + __uint_as_float(b<<16);
  float hi = __uint_as_float(a&0xffff0000u)   + __uint_as_float(b&0xffff0000u);
  return (u32)f2bf(lo) | ((u32)f2bf(hi)<<16);
}

// ============ workspace layout (bytes) — total ~194 MB ============
static constexpr size_t alup(size_t x){ return (x + 255) & ~(size_t)255; }
static constexpr size_t OFF_MEAN = 0;
static constexpr size_t OFF_RSTD = OFF_MEAN + alup((size_t)NRW*4);
static constexpr size_t OFF_STD  = OFF_RSTD + alup((size_t)NRW*4);
static constexpr size_t OFF_XT   = OFF_STD  + alup((size_t)NRW*4);
static constexpr size_t OFF_PE   = OFF_XT   + alup((size_t)NRW*L_*4);
static constexpr size_t OFF_W1T  = OFF_PE   + alup((size_t)P_*D_*4);
static constexpr size_t OFF_W2T  = OFF_W1T  + alup((size_t)E_*H_*D_*2);
static constexpr size_t OFF_WHT  = OFF_W2T  + alup((size_t)E_*D_*H_*2);
static constexpr size_t OFF_T    = OFF_WHT  + alup((size_t)96*DP_*2);      // tokens bf16; later ALIASED as Ahead
static constexpr size_t OFF_TOPI = OFF_T    + alup((size_t)NTOK*D_*2);
static constexpr size_t OFF_GATE = OFF_TOPI + alup((size_t)NTOK*4);
static constexpr size_t OFF_CNTR = OFF_GATE + alup((size_t)NTOK*8);
static constexpr size_t OFF_BTOK = OFF_CNTR + alup((size_t)1024);
static constexpr size_t OFF_BGT  = OFF_BTOK + alup((size_t)2*NBUCK*4);
static constexpr size_t OFF_OUT  = OFF_BGT  + alup((size_t)2*NBUCK*4);     // combined token outputs bf16 [token][d]
static constexpr size_t OFF_DEC  = OFF_OUT  + alup((size_t)NTOK*D_*2);
static constexpr size_t OFF_MEAND= OFF_DEC  + alup((size_t)NRW*96*4);
static constexpr size_t OFF_RSTDD= OFF_MEAND+ alup((size_t)NRW*8);
static constexpr size_t OFF_PED  = OFF_RSTDD+ alup((size_t)NRW*8);
static constexpr size_t OFF_WVG  = OFF_PED  + alup((size_t)P_*D_*8);
static constexpr size_t OFF_PEG  = OFF_WVG  + alup((size_t)16*8*8);
// end = OFF_PEG + 4KB  ≈ 194 MB

// counters: cd=double[9] at OFF_CNTR (sumP[8], zsum); ints at OFF_CNTR+128:
// ci[0..7]=cnt1 ci[8..15]=cnt2 ci[16..23]=cur1 ci[24..31]=cur2
// ci[32..40]=start1 ci[41..49]=start2 ci[50..58]=bstart1 ci[59..67]=bstart2

// ============ kernels ============

// transpose x_enc (B,L,NV) -> xT[(b*NV+v)*L + l]
__global__ void k_xt(const float* __restrict__ x, float* __restrict__ xT){
  __shared__ float tile[32][33];
  int b = blockIdx.z;
  int v0 = blockIdx.x*32, l0 = blockIdx.y*32;
  int tx = threadIdx.x, ty = threadIdx.y;
  for(int i=ty;i<32;i+=8){
    int l = l0+i, v = v0+tx;
    tile[i][tx] = (v<NV_) ? x[((size_t)b*L_ + l)*NV_ + v] : 0.f;
  }
  __syncthreads();
  for(int i=ty;i<32;i+=8){
    int v = v0+i, l = l0+tx;
    if(v<NV_) xT[((size_t)(b*NV_+v))*L_ + l] = tile[tx][i];
  }
}

// fp64 stats
__global__ void k_stats(const float* __restrict__ xT, float* meanp, float* rstdp, float* stdp,
                        double* meand, double* rstdd){
  __shared__ double s1[256], s2[256];
  int r = blockIdx.x, t = threadIdx.x;
  double a = (double)xT[(size_t)r*L_ + t], b = (double)xT[(size_t)r*L_ + 256 + t];
  s1[t]=a+b; s2[t]=a*a+b*b;
  __syncthreads();
  for(int o=128;o>0;o>>=1){ if(t<o){ s1[t]+=s1[t+o]; s2[t]+=s2[t+o]; } __syncthreads(); }
  if(t==0){
    double m = s1[0]*(1.0/512.0);
    double var = s2[0]*(1.0/512.0) - m*m;
    double sd = sqrt(var + 1e-5);
    meanp[r]=(float)m; stdp[r]=(float)sd; rstdp[r]=(float)(1.0/sd);
    meand[r]=m; rstdd[r]=1.0/sd;
  }
}

// PE in double, stored float (np float32 semantics) + double promotion of the float
__global__ void k_pe(float* pef, double* ped){
  int i = blockIdx.x*256 + threadIdx.x;   // 8192
  int p = i>>7, d = i&127;
  int k = d>>1;
  double div = exp(-(double)(2*k) * (9.210340371976184 /128.0)); // ln(10000)/128
  double ang = (double)p * div;
  double v = (d&1) ? cos(ang) : sin(ang);
  float vf = (float)v;
  pef[i] = vf;
  ped[i] = (double)vf;
}

// precompute Wvg = W_val@W_g (16x8) and peg = pe@W_g (64x8) in fp64
__global__ void k_prep(const float* __restrict__ Wval, const float* __restrict__ Wg,
                       const double* __restrict__ ped, double* __restrict__ Wvg,
                       double* __restrict__ peg){
  int t = threadIdx.x;
  if(t<128){
    int j = t>>3, e = t&7;
    double acc = 0.0;
    for(int d=0;d<128;d++) acc += (double)Wval[j*128+d] * (double)Wg[d*8+e];
    Wvg[t] = acc;
  }
  for(int q=t;q<512;q+=256){
    int p = q>>3, e = q&7;
    double acc = 0.0;
    for(int d=0;d<128;d++) acc += ped[p*128+d] * (double)Wg[d*8+e];
    peg[q] = acc;
  }
}

// fp32 [batch][R][C] -> bf16 [batch][C][R]
__global__ void k_wt(const float* __restrict__ in, u16* __restrict__ outp, int R, int C){
  __shared__ float tile[32][33];
  int e = blockIdx.z;
  int c0 = blockIdx.x*32, r0 = blockIdx.y*32;
  const float* src = in + (size_t)e*R*C;
  u16* dst = outp + (size_t)e*R*C;
  int tx=threadIdx.x, ty=threadIdx.y;
  for(int i=ty;i<32;i+=8){
    int r=r0+i, c=c0+tx;
    tile[i][tx] = (r<R && c<C) ? src[(size_t)r*C+c] : 0.f;
  }
  __syncthreads();
  for(int i=ty;i<32;i+=8){
    int c=c0+i, r=r0+tx;
    if(c<C && r<R) dst[(size_t)c*R + r] = f2bf(tile[tx][i]);
  }
}

// per (b,v) row: patch embed + PE -> bf16 tokens (no gating here)
__global__ __launch_bounds__(256) void k_embed(
    const float* __restrict__ xT, const float* __restrict__ meanp, const float* __restrict__ rstdp,
    const float* __restrict__ Wval, const float* __restrict__ pe,
    u16* __restrict__ tglob)
{
  __shared__ float xn[512];
  __shared__ float wv[16*128];
  int r = blockIdx.x, t = threadIdx.x;
  float mean = meanp[r], rstd = rstdp[r];
  xn[t]     = (xT[(size_t)r*L_ + t]       - mean)*rstd;
  xn[t+256] = (xT[(size_t)r*L_ + 256 + t] - mean)*rstd;
  for(int i=t;i<2048;i+=256) wv[i] = Wval[i];
  __syncthreads();

  int lane64 = t & 63;
  int d0 = lane64*2;
  int p0 = t >> 6;
  for(int p=p0;p<64;p+=4){
    float2 pw = *(const float2*)(pe + p*128 + d0);
    float a0 = pw.x, a1 = pw.y;
    int base = p*8;
    #pragma unroll
    for(int j=0;j<16;j++){
      int l = base + j; l = (l>511)?511:l;     // edge pad
      float xv = xn[l];
      float2 w = *(const float2*)(wv + j*128 + d0);
      a0 += xv*w.x; a1 += xv*w.y;
    }
    u32 packed = (u32)f2bf(a0) | ((u32)f2bf(a1)<<16);
    *(u32*)(tglob + ((size_t)(r*64+p)*128 + d0)) = packed;
  }
}

// fp64 gating: logits[p][e] = peg[p][e] + sum_j xn[p*8+j]*Wvg[j][e]; top-2 + aux
__global__ __launch_bounds__(256) void k_gate(
    const float* __restrict__ xT, const double* __restrict__ meand, const double* __restrict__ rstdd,
    const double* __restrict__ Wvg, const double* __restrict__ peg,
    int* __restrict__ topip, float2* __restrict__ gatep,
    double* __restrict__ cd, int* __restrict__ ci)
{
  __shared__ double xn[512];
  __shared__ double lgt[64][9];
  int r = blockIdx.x, t = threadIdx.x;
  double m = meand[r], rs = rstdd[r];
  xn[t]     = ((double)xT[(size_t)r*L_ + t]       - m)*rs;
  xn[t+256] = ((double)xT[(size_t)r*L_ + 256 + t] - m)*rs;
  __syncthreads();
  for(int q=t;q<512;q+=256){
    int p = q>>3, e = q&7;
    double acc = peg[q];
    #pragma unroll
    for(int j=0;j<16;j++){
      int l = p*8+j; l = (l>511)?511:l;
      acc += xn[l]*Wvg[j*8+e];
    }
    lgt[p][e] = acc;
  }
  __syncthreads();
  if(t<64){
    int token = r*64 + t;
    double l0[8];
    #pragma unroll
    for(int e=0;e<8;e++) l0[e]=lgt[t][e];
    double mx=l0[0];
    #pragma unroll
    for(int e=1;e<8;e++) mx = fmax(mx,l0[e]);
    double pr[8]; double sum=0.0;
    #pragma unroll
    for(int e=0;e<8;e++){ pr[e]=exp(l0[e]-mx); sum+=pr[e]; }
    double inv = 1.0/sum;
    #pragma unroll
    for(int e=0;e<8;e++) pr[e]*=inv;
    int i1=0; double v1=l0[0];
    #pragma unroll
    for(int e=1;e<8;e++) if(l0[e]>v1){v1=l0[e]; i1=e;}
    int i2=-1; double v2=-1e300;
    #pragma unroll
    for(int e=0;e<8;e++) if(e!=i1 && l0[e]>v2){v2=l0[e]; i2=e;}
    topip[token] = i1 | (i2<<8);
    gatep[token] = make_float2((float)pr[i1], (float)pr[i2]);
    double lse = mx + log(sum);
    // wave-64 reductions (t<64 == wave 0, fully active)
    #pragma unroll
    for(int e=0;e<8;e++){
      double v = pr[e];
      for(int o=32;o>0;o>>=1) v += __shfl_down(v,o);
      if(t==0) atomicAdd(&cd[e], v);
    }
    {
      double z = lse*lse;
      for(int o=32;o>0;o>>=1) z += __shfl_down(z,o);
      if(t==0) atomicAdd(&cd[8], z);
    }
    #pragma unroll
    for(int e=0;e<8;e++){
      u64 m1 = __ballot(i1==e);
      u64 m2 = __ballot(i2==e);
      if(t==0){
        atomicAdd(&ci[e],   (int)__popcll(m1));
        atomicAdd(&ci[8+e], (int)__popcll(m2));
      }
    }
  }
}

__global__ void k_aux(double* cd, int* ci, float* dout){
  if(threadIdx.x==0 && blockIdx.x==0){
    const double invN = 1.0/(double)NTOK;
    double bal = 0.0;
    int es1=0, bs1=0, es2=0, bs2=0;
    for(int e=0;e<8;e++){
      int c1 = ci[e], c2 = ci[8+e];
      bal += (cd[e]*invN) * ((double)(c1+c2) * invN * 0.5);
      ci[32+e]=es1; ci[16+e]=es1; ci[50+e]=bs1;
      ci[41+e]=es2; ci[24+e]=es2; ci[59+e]=bs2;
      es1 += c1; bs1 += (c1+127)>>7;
      es2 += c2; bs2 += (c2+127)>>7;
    }
    ci[40]=es1; ci[58]=bs1;
    ci[49]=es2; ci[67]=bs2;
    dout[493056] = (float)(0.01*8.0*bal + 0.001*(cd[8]*invN));
  }
}

__global__ __launch_bounds__(256) void k_scatter(const int* __restrict__ topip,
    const float2* __restrict__ gatep, int* __restrict__ ci,
    int* __restrict__ btok, float* __restrict__ bgt){
  __shared__ int lc[16]; __shared__ int lb[16];
  int t = threadIdx.x;
  int token = blockIdx.x*256 + t;
  if(t<16) lc[t]=0;
  __syncthreads();
  int ti = topip[token];
  float2 g = gatep[token];
  int e1 = ti & 255, e2 = (ti>>8)&255;
  int r1 = atomicAdd(&lc[e1],1);
  int r2 = atomicAdd(&lc[8+e2],1);
  __syncthreads();
  if(t<8)            lb[t] = atomicAdd(&ci[16+t],   lc[t]);
  else if(t<16)      lb[t] = atomicAdd(&ci[24+t-8], lc[t]);
  __syncthreads();
  int p1 = lb[e1]+r1, p2 = lb[8+e2]+r2;
  btok[p1] = token;         bgt[p1] = g.x;
  btok[NBUCK+p2] = token;   bgt[NBUCK+p2] = g.y;
}

// fused per-expert FFN, one slot per pass.
// pass 0: OUT[token] = g1*(h+b2)   pass 1: OUT[token] += g2*(h+b2)  (race-free: token unique per pass)
__global__ __launch_bounds__(256,2) void k_expert(
    const u16* __restrict__ tglob,
    const u16* __restrict__ W1T, const u16* __restrict__ W2T,
    const float* __restrict__ b1g, const float* __restrict__ b2g,
    const int* __restrict__ ci,
    const int* __restrict__ btok, const float* __restrict__ bgt,
    u16* __restrict__ outg, int slot)
{
  __shared__ __align__(16) u16 As[128*128];   // 32 KB
  __shared__ __align__(16) u16 Ws[128*64];    // 16 KB
  __shared__ __align__(16) u16 Ss[128*64];    // 16 KB  (total 64 KB)

  int bid = blockIdx.x, t = threadIdx.x;
  int stB = 32 + slot*9, bsB = 50 + slot*9;
  int boff = slot*NBUCK;
  int totalB = ci[bsB+8];
  if(bid >= totalB) return;
  int e = 0;
  #pragma unroll
  for(int k2=1;k2<8;k2++) if(bid >= ci[bsB+k2]) e = k2;
  int row0 = ci[stB+e] + (bid - ci[bsB+e])*128;
  int rend = ci[stB+e+1];

  if(t<128){
    int pos = row0+t;
    ((int*)Ws)[t] = (pos<rend) ? btok[boff+pos] : -1;
  }
  __syncthreads();
  { // gather A rows from token buffer
    int lr = t>>1, half = t&1;
    int token = ((int*)Ws)[lr];
    int tk = (token>=0) ? token : 0;
    const u16* src = tglob + (size_t)tk*128 + half*64;
    #pragma unroll
    for(int i=0;i<8;i++){
      int kb = half*8 + i;
      uint4 v = *(const uint4*)(src + i*8);
      *(uint4*)(As + lr*128 + ((kb ^ (lr&7))<<3)) = v;
    }
  }
  __syncthreads();

  int wid = t>>6, lane = t&63;
  int wr = wid>>1, wc = wid&1;
  int quad = lane>>4, li = lane&15;

  f32x4 accO[4][4];
  #pragma unroll
  for(int i=0;i<4;i++)
    #pragma unroll
    for(int j=0;j<4;j++) accO[i][j] = (f32x4){0.f,0.f,0.f,0.f};

  float myb2[4];
  #pragma unroll
  for(int nt=0;nt<4;nt++) myb2[nt] = b2g[e*128 + wc*64 + nt*16 + li];

  for(int hc=0;hc<8;hc++){
    { // stage W1 chunk [64h][128d]
      int hr = t>>2, qq = t&3;
      const u16* src = W1T + ((size_t)e*H_ + hc*64 + hr)*128 + qq*32;
      #pragma unroll
      for(int i=0;i<4;i++){
        int kb = qq*4 + i;
        uint4 v = *(const uint4*)(src + i*8);
        *(uint4*)(Ws + hr*128 + ((kb ^ (hr&7))<<3)) = v;
      }
    }
    __syncthreads();
    // GEMM1: S(128x64) = A(128x128) @ W1c
    f32x4 acc1[4][2];
    #pragma unroll
    for(int i=0;i<4;i++){ acc1[i][0]=(f32x4){0,0,0,0}; acc1[i][1]=(f32x4){0,0,0,0}; }
    #pragma unroll
    for(int ks=0;ks<4;ks++){
      bf16x8 af[4], bfg[2];
      int kb = ks*4 + quad;
      #pragma unroll
      for(int mt=0;mt<4;mt++){
        int row = wr*64 + mt*16 + li;
        af[mt] = *(const bf16x8*)(As + row*128 + ((kb ^ (row&7))<<3));
      }
      #pragma unroll
      for(int nt=0;nt<2;nt++){
        int hrow = wc*32 + nt*16 + li;
        bfg[nt] = *(const bf16x8*)(Ws + hrow*128 + ((kb ^ (hrow&7))<<3));
      }
      #pragma unroll
      for(int mt=0;mt<4;mt++)
        #pragma unroll
        for(int nt=0;nt<2;nt++)
          acc1[mt][nt] = MFMA16(af[mt], bfg[nt], acc1[mt][nt]);
    }
    float b1v[2];
    #pragma unroll
    for(int nt=0;nt<2;nt++) b1v[nt] = b1g[e*H_ + hc*64 + wc*32 + nt*16 + li];
    #pragma unroll
    for(int mt=0;mt<4;mt++)
      #pragma unroll
      for(int nt=0;nt<2;nt++)
        #pragma unroll
        for(int rg=0;rg<4;rg++){
          int row = wr*64 + mt*16 + quad*4 + rg;
          int d   = wc*32 + nt*16 + li;
          float g = gelu_f(acc1[mt][nt][rg] + b1v[nt]);
          Ss[row*64 + (((d>>3) ^ (row&7))<<3) + (d&7)] = f2bf(g);
        }
    __syncthreads();
    { // stage W2 chunk [128d][64h]
      int dr = t>>1, hh = t&1;
      const u16* src = W2T + ((size_t)e*D_ + dr)*H_ + hc*64 + hh*32;
      #pragma unroll
      for(int i=0;i<4;i++){
        int kb = hh*4 + i;
        uint4 v = *(const uint4*)(src + i*8);
        *(uint4*)(Ws + dr*64 + ((kb ^ (dr&7))<<3)) = v;
      }
    }
    __syncthreads();
    // GEMM2: accO += S(128x64) @ W2c
    #pragma unroll
    for(int ks=0;ks<2;ks++){
      bf16x8 af[4], bfg[4];
      int kb = ks*4 + quad;
      #pragma unroll
      for(int mt=0;mt<4;mt++){
        int row = wr*64 + mt*16 + li;
        af[mt] = *(const bf16x8*)(Ss + row*64 + ((kb ^ (row&7))<<3));
      }
      #pragma unroll
      for(int nt=0;nt<4;nt++){
        int drow = wc*64 + nt*16 + li;
        bfg[nt] = *(const bf16x8*)(Ws + drow*64 + ((kb ^ (drow&7))<<3));
      }
      #pragma unroll
      for(int mt=0;mt<4;mt++)
        #pragma unroll
        for(int nt=0;nt<4;nt++)
          accO[mt][nt] = MFMA16(af[mt], bfg[nt], accO[mt][nt]);
    }
    __syncthreads();
  }

  // epilogue: reload token/gate, scale, transpose via As, coalesced (RMW) store
  if(t<128){
    int pos = row0+t;
    bool v = pos<rend;
    ((float*)Ss)[t]   = v ? bgt[boff+pos]  : 0.f;
    ((int*)Ss)[128+t] = v ? btok[boff+pos] : -1;
  }
  __syncthreads();
  #pragma unroll
  for(int mt=0;mt<4;mt++)
    #pragma unroll
    for(int nt=0;nt<4;nt++)
      #pragma unroll
      for(int rg=0;rg<4;rg++){
        int row = wr*64 + mt*16 + quad*4 + rg;
        int d   = wc*64 + nt*16 + li;
        float v = (accO[mt][nt][rg] + myb2[nt]) * ((float*)Ss)[row];
        As[row*128 + (((d>>3) ^ (row&7))<<3) + (d&7)] = f2bf(v);
      }
  __syncthreads();
  {
    int lr = t>>1, half = t&1;
    int token = ((int*)Ss)[128+lr];
    if(token>=0){
      u16* dst = outg + (size_t)token*128 + half*64;
      #pragma unroll
      for(int i=0;i<8;i++){
        int kb = half*8 + i;
        uint4 v = *(const uint4*)(As + lr*128 + ((kb ^ (lr&7))<<3));
        if(slot==1){
          uint4 o = *(const uint4*)(dst + i*8);
          v.x = bfadd2(v.x, o.x); v.y = bfadd2(v.y, o.y);
          v.z = bfadd2(v.z, o.z); v.w = bfadd2(v.w, o.w);
        }
        *(uint4*)(dst + i*8) = v;
      }
    }
  }
}

// OUT[r*64+p][d] -> Ahead[r][d*64+p]  (bf16 transpose per row-block)
__global__ __launch_bounds__(256) void k_trans(const u16* __restrict__ outg, u16* __restrict__ Ahead){
  __shared__ u16 s[64][136];
  int r = blockIdx.x, t = threadIdx.x;
  {
    int p = t>>2, dc = (t&3)*32;
    const u16* src = outg + ((size_t)(r*64+p))*128 + dc;
    #pragma unroll
    for(int i=0;i<4;i++){
      uint4 v = *(const uint4*)(src + i*8);
      *(uint4*)(&s[p][dc + i*8]) = v;
    }
  }
  __syncthreads();
  {
    int d = t>>1, pr = (t&1)*32;
    u32 wbuf[16];
    #pragma unroll
    for(int i=0;i<16;i++){
      u32 lo = s[pr + 2*i    ][d];
      u32 hi = s[pr + 2*i + 1][d];
      wbuf[i] = lo | (hi<<16);
    }
    u16* dst = Ahead + (size_t)r*DP_ + d*64 + pr;
    #pragma unroll
    for(int i=0;i<4;i++) *(uint4*)(dst + i*8) = *(uint4*)(wbuf + i*4);
  }
}

// head GEMM: dec[r][o] += A[r][:]@WhT[o][:]  (M=64 tiles, K split 4-way)
__global__ __launch_bounds__(256) void k_head(const u16* __restrict__ Ahead,
    const u16* __restrict__ WhT, float* __restrict__ dec){
  __shared__ float red[64*96];
  int bid = blockIdx.x;
  int mb = bid>>2, kseg = bid&3;
  int r0 = mb*64;
  int t = threadIdx.x, wid = t>>6, lane = t&63;
  int quad = lane>>4, li = lane&15;
  for(int i=t;i<6144;i+=256) red[i]=0.f;
  __syncthreads();
  size_t kbase = (size_t)kseg*2048 + (size_t)wid*512;
  f32x4 acc[4][6];
  #pragma unroll
  for(int i=0;i<4;i++)
    #pragma unroll
    for(int j=0;j<6;j++) acc[i][j]=(f32x4){0,0,0,0};
  bf16x8 zf = {0,0,0,0,0,0,0,0};
  for(int ks=0;ks<16;ks++){
    size_t k = kbase + ks*32 + quad*8;
    bf16x8 af[4], bfg[6];
    #pragma unroll
    for(int mt=0;mt<4;mt++){
      int row = r0 + mt*16 + li;
      af[mt] = (row<NRW) ? *(const bf16x8*)(Ahead + (size_t)row*DP_ + k) : zf;
    }
    #pragma unroll
    for(int nt=0;nt<6;nt++){
      int n = nt*16 + li;
      bfg[nt] = *(const bf16x8*)(WhT + (size_t)n*DP_ + k);
    }
    #pragma unroll
    for(int mt=0;mt<4;mt++)
      #pragma unroll
      for(int nt=0;nt<6;nt++)
        acc[mt][nt] = MFMA16(af[mt], bfg[nt], acc[mt][nt]);
  }
  #pragma unroll
  for(int mt=0;mt<4;mt++)
    #pragma unroll
    for(int nt=0;nt<6;nt++)
      #pragma unroll
      for(int rg=0;rg<4;rg++){
        int m = mt*16 + quad*4 + rg;
        int n = nt*16 + li;
        atomicAdd(&red[m*96+n], acc[mt][nt][rg]);
      }
  __syncthreads();
  for(int i=t;i<6144;i+=256){
    int m = i/96, n = i - m*96;
    if(r0+m < NRW) atomicAdd(&dec[(size_t)(r0+m)*96 + n], red[i]);
  }
}

// transpose + bias + denorm: out[b][o][v] = (dec[r][o]+b_head[o])*std[r]+mean[r]
__global__ void k_final(const float* __restrict__ dec, const float* __restrict__ bhead,
    const float* __restrict__ stdp, const float* __restrict__ meanp, float* __restrict__ outp){
  __shared__ float s[64*97];
  int b = blockIdx.y, v0 = blockIdx.x*64;
  int t = threadIdx.x;
  for(int i=t;i<6144;i+=256){
    int vi = i/96, o = i - vi*96;
    int v = v0+vi;
    s[vi*97+o] = (v<NV_) ? dec[(size_t)(b*NV_+v)*96 + o] : 0.f;
  }
  __syncthreads();
  for(int i=t;i<6144;i+=256){
    int o = i>>6, vi = i&63;
    int v = v0+vi;
    if(v<NV_){
      int r = b*NV_+v;
      outp[((size_t)b*96 + o)*NV_ + v] = (s[vi*97+o] + bhead[o])*stdp[r] + meanp[r];
    }
  }
}

// ============ launcher ============
extern "C" void kernel_launch(void* const* d_in, const int* in_sizes, int n_in,
                              void* d_out, int out_size, void* d_ws, size_t ws_size,
                              hipStream_t stream){
  const float* x_enc = (const float*)d_in[0];
  const float* W_val = (const float*)d_in[4];
  const float* W_g   = (const float*)d_in[5];
  const float* W1    = (const float*)d_in[6];
  const float* b1    = (const float*)d_in[7];
  const float* W2    = (const float*)d_in[8];
  const float* b2    = (const float*)d_in[9];
  const float* W_head= (const float*)d_in[10];
  const float* b_head= (const float*)d_in[11];
  float* outp = (float*)d_out;
  char* ws = (char*)d_ws;

  float* meanp = (float*)(ws+OFF_MEAN);
  float* rstdp = (float*)(ws+OFF_RSTD);
  float* stdp  = (float*)(ws+OFF_STD);
  float* xT    = (float*)(ws+OFF_XT);
  float* pe    = (float*)(ws+OFF_PE);
  u16*   W1T   = (u16*)(ws+OFF_W1T);
  u16*   W2T   = (u16*)(ws+OFF_W2T);
  u16*   WhT   = (u16*)(ws+OFF_WHT);
  u16*   tglob = (u16*)(ws+OFF_T);
  u16*   Ahead = (u16*)(ws+OFF_T);      // aliases token buffer (dead after expert passes)
  int*   topip = (int*)(ws+OFF_TOPI);
  float2* gatep= (float2*)(ws+OFF_GATE);
  double* cd   = (double*)(ws+OFF_CNTR);
  int*   ci    = (int*)(ws+OFF_CNTR+128);
  int*   btok  = (int*)(ws+OFF_BTOK);
  float* bgt   = (float*)(ws+OFF_BGT);
  u16*   outg  = (u16*)(ws+OFF_OUT);
  float* dec   = (float*)(ws+OFF_DEC);
  double* meand= (double*)(ws+OFF_MEAND);
  double* rstdd= (double*)(ws+OFF_RSTDD);
  double* ped  = (double*)(ws+OFF_PED);
  double* Wvg  = (double*)(ws+OFF_WVG);
  double* peg  = (double*)(ws+OFF_PEG);

  hipMemsetAsync(ws+OFF_CNTR, 0, 1024, stream);
  hipMemsetAsync(ws+OFF_DEC, 0, (size_t)NRW*96*4, stream);

  k_xt<<<dim3(11,16,B_), dim3(32,8), 0, stream>>>(x_enc, xT);
  k_stats<<<NRW, 256, 0, stream>>>(xT, meanp, rstdp, stdp, meand, rstdd);
  k_pe<<<32, 256, 0, stream>>>(pe, ped);
  k_prep<<<1, 256, 0, stream>>>(W_val, W_g, ped, Wvg, peg);
  k_wt<<<dim3(16,4,E_), dim3(32,8), 0, stream>>>(W1, W1T, 128, 512);
  k_wt<<<dim3(4,16,E_), dim3(32,8), 0, stream>>>(W2, W2T, 512, 128);
  k_wt<<<dim3(3,256,1), dim3(32,8), 0, stream>>>(W_head, WhT, 8192, 96);
  k_embed<<<NRW, 256, 0, stream>>>(xT, meanp, rstdp, W_val, pe, tglob);
  k_gate<<<NRW, 256, 0, stream>>>(xT, meand, rstdd, Wvg, peg, topip, gatep, cd, ci);
  k_aux<<<1, 64, 0, stream>>>(cd, ci, outp);
  k_scatter<<<NTOK/256, 256, 0, stream>>>(topip, gatep, ci, btok, bgt);
  k_expert<<<2576, 256, 0, stream>>>(tglob, W1T, W2T, b1, b2, ci, btok, bgt, outg, 0);
  k_expert<<<2576, 256, 0, stream>>>(tglob, W1T, W2T, b1, b2, ci, btok, bgt, outg, 1);
  k_trans<<<NRW, 256, 0, stream>>>(outg, Ahead);
  k_head<<<324, 256, 0, stream>>>(Ahead, WhT, dec);
  k_final<<<dim3(6,B_), 256, 0, stream>>>(dec, b_head, stdp, meanp, outp);
}

// Round 4
// 838.837 us; speedup vs baseline: 2.3741x; 2.3741x over previous
//
#include <hip/hip_runtime.h>
#include <hip/hip_bf16.h>

typedef unsigned short u16;
typedef unsigned int   u32;
typedef unsigned long long u64;
typedef __attribute__((ext_vector_type(8))) short bf16x8;
typedef __attribute__((ext_vector_type(4))) float f32x4;

#define MFMA16(a,b,c) __builtin_amdgcn_mfma_f32_16x16x32_bf16(a,b,c,0,0,0)

// ---- problem dims ----
#define NV_   321
#define B_    16
#define L_    512
#define D_    128
#define P_    64
#define E_    8
#define H_    512
#define NRW   5136        // B*NV
#define NTOK  328704      // NRW*P
#define DP_   8192        // D*P
#define NBUCK 329728      // NTOK + 8*128 padding

static __device__ __forceinline__ u16 f2bf(float f){
  __hip_bfloat16 h = __float2bfloat16(f);
  return *reinterpret_cast<u16*>(&h);
}

// fast tanh-form GELU (hw v_exp + v_rcp); max dev vs erf form ~3e-4
static __device__ __forceinline__ float gelu_f(float x){
  float a = 1.5957691216057308f*x*(1.0f + 0.044715f*x*x);   // 2*u
  float e = __expf(a);
  float th = 1.0f - 2.0f*__builtin_amdgcn_rcpf(e + 1.0f);
  return 0.5f*x*(1.0f+th);
}

static __device__ __forceinline__ u32 bfadd2(u32 a, u32 b){
  float lo = __uint_as_float(a<<16)           + __uint_as_float(b<<16);
  float hi = __uint_as_float(a&0xffff0000u)   + __uint_as_float(b&0xffff0000u);
  return (u32)f2bf(lo) | ((u32)f2bf(hi)<<16);
}

// swizzle for 128B-period LDS rows: rows r and r+8 must land differently
static __device__ __forceinline__ int swz(int r){ return (r ^ (r>>3)) & 7; }

// ============ workspace layout (bytes) ============
static constexpr size_t alup(size_t x){ return (x + 255) & ~(size_t)255; }
static constexpr size_t OFF_MEAN = 0;
static constexpr size_t OFF_RSTD = OFF_MEAN + alup((size_t)NRW*4);
static constexpr size_t OFF_STD  = OFF_RSTD + alup((size_t)NRW*4);
static constexpr size_t OFF_XT   = OFF_STD  + alup((size_t)NRW*4);   // later ALIASED as dec4
static constexpr size_t OFF_PE   = OFF_XT   + alup((size_t)NRW*L_*4);
static constexpr size_t OFF_W1T  = OFF_PE   + alup((size_t)P_*D_*4);
static constexpr size_t OFF_W2T  = OFF_W1T  + alup((size_t)E_*H_*D_*2);
static constexpr size_t OFF_WHT  = OFF_W2T  + alup((size_t)E_*D_*H_*2);
static constexpr size_t OFF_T    = OFF_WHT  + alup((size_t)96*DP_*2);      // tokens bf16; later ALIASED as Ahead
static constexpr size_t OFF_TOPI = OFF_T    + alup((size_t)NTOK*D_*2);
static constexpr size_t OFF_GATE = OFF_TOPI + alup((size_t)NTOK*4);
static constexpr size_t OFF_CNTR = OFF_GATE + alup((size_t)NTOK*8);
static constexpr size_t OFF_BTOK = OFF_CNTR + alup((size_t)1024);
static constexpr size_t OFF_BGT  = OFF_BTOK + alup((size_t)2*NBUCK*4);
static constexpr size_t OFF_OUT  = OFF_BGT  + alup((size_t)2*NBUCK*4);     // combined token outputs bf16 [token][d]
static constexpr size_t OFF_DEC  = OFF_OUT  + alup((size_t)NTOK*D_*2);     // (unused now, kept for layout stability)
static constexpr size_t OFF_MEAND= OFF_DEC  + alup((size_t)NRW*96*4);
static constexpr size_t OFF_RSTDD= OFF_MEAND+ alup((size_t)NRW*8);
static constexpr size_t OFF_PED  = OFF_RSTDD+ alup((size_t)NRW*8);
static constexpr size_t OFF_WVG  = OFF_PED  + alup((size_t)P_*D_*8);
static constexpr size_t OFF_PEG  = OFF_WVG  + alup((size_t)16*8*8);
static constexpr size_t OFF_PG   = OFF_PEG  + alup((size_t)P_*E_*8);
static constexpr size_t OFF_PI   = OFF_PG   + alup((size_t)NRW*12*4);
// end = OFF_PI + NRW*64  ≈ 195 MB

// ci ints at OFF_CNTR+128: [16..23]=cur1 [24..31]=cur2
// [32..40]=start1 [41..49]=start2 [50..58]=bstart1 [59..67]=bstart2

// ============ kernels ============

// transpose x_enc (B,L,NV) -> xT[(b*NV+v)*L + l]
__global__ void k_xt(const float* __restrict__ x, float* __restrict__ xT){
  __shared__ float tile[32][33];
  int b = blockIdx.z;
  int v0 = blockIdx.x*32, l0 = blockIdx.y*32;
  int tx = threadIdx.x, ty = threadIdx.y;
  for(int i=ty;i<32;i+=8){
    int l = l0+i, v = v0+tx;
    tile[i][tx] = (v<NV_) ? x[((size_t)b*L_ + l)*NV_ + v] : 0.f;
  }
  __syncthreads();
  for(int i=ty;i<32;i+=8){
    int v = v0+i, l = l0+tx;
    if(v<NV_) xT[((size_t)(b*NV_+v))*L_ + l] = tile[tx][i];
  }
}

// fp64 stats
__global__ void k_stats(const float* __restrict__ xT, float* meanp, float* rstdp, float* stdp,
                        double* meand, double* rstdd){
  __shared__ double s1[256], s2[256];
  int r = blockIdx.x, t = threadIdx.x;
  double a = (double)xT[(size_t)r*L_ + t], b = (double)xT[(size_t)r*L_ + 256 + t];
  s1[t]=a+b; s2[t]=a*a+b*b;
  __syncthreads();
  for(int o=128;o>0;o>>=1){ if(t<o){ s1[t]+=s1[t+o]; s2[t]+=s2[t+o]; } __syncthreads(); }
  if(t==0){
    double m = s1[0]*(1.0/512.0);
    double var = s2[0]*(1.0/512.0) - m*m;
    double sd = sqrt(var + 1e-5);
    meanp[r]=(float)m; stdp[r]=(float)sd; rstdp[r]=(float)(1.0/sd);
    meand[r]=m; rstdd[r]=1.0/sd;
  }
}

// PE in double, stored float (np float32 semantics) + double promotion of the float
__global__ void k_pe(float* pef, double* ped){
  int i = blockIdx.x*256 + threadIdx.x;   // 8192
  int p = i>>7, d = i&127;
  int k = d>>1;
  double div = exp(-(double)(2*k) * (9.210340371976184 /128.0)); // ln(10000)/128
  double ang = (double)p * div;
  double v = (d&1) ? cos(ang) : sin(ang);
  float vf = (float)v;
  pef[i] = vf;
  ped[i] = (double)vf;
}

// precompute Wvg = W_val@W_g (16x8) and peg = pe@W_g (64x8) in fp64
__global__ void k_prep(const float* __restrict__ Wval, const float* __restrict__ Wg,
                       const double* __restrict__ ped, double* __restrict__ Wvg,
                       double* __restrict__ peg){
  int t = threadIdx.x;
  if(t<128){
    int j = t>>3, e = t&7;
    double acc = 0.0;
    for(int d=0;d<128;d++) acc += (double)Wval[j*128+d] * (double)Wg[d*8+e];
    Wvg[t] = acc;
  }
  for(int q=t;q<512;q+=256){
    int p = q>>3, e = q&7;
    double acc = 0.0;
    for(int d=0;d<128;d++) acc += ped[p*128+d] * (double)Wg[d*8+e];
    peg[q] = acc;
  }
}

// fp32 [batch][R][C] -> bf16 [batch][C][R]
__global__ void k_wt(const float* __restrict__ in, u16* __restrict__ outp, int R, int C){
  __shared__ float tile[32][33];
  int e = blockIdx.z;
  int c0 = blockIdx.x*32, r0 = blockIdx.y*32;
  const float* src = in + (size_t)e*R*C;
  u16* dst = outp + (size_t)e*R*C;
  int tx=threadIdx.x, ty=threadIdx.y;
  for(int i=ty;i<32;i+=8){
    int r=r0+i, c=c0+tx;
    tile[i][tx] = (r<R && c<C) ? src[(size_t)r*C+c] : 0.f;
  }
  __syncthreads();
  for(int i=ty;i<32;i+=8){
    int c=c0+i, r=r0+tx;
    if(c<C && r<R) dst[(size_t)c*R + r] = f2bf(tile[tx][i]);
  }
}

// per (b,v) row: patch embed + PE -> bf16 tokens. W_val column in registers,
// xn via wave-uniform float4 LDS reads.
__global__ __launch_bounds__(256) void k_embed(
    const float* __restrict__ xT, const float* __restrict__ meanp, const float* __restrict__ rstdp,
    const float* __restrict__ Wval, const float* __restrict__ pe,
    u16* __restrict__ tglob)
{
  __shared__ __align__(16) float xn[520];
  int r = blockIdx.x, t = threadIdx.x;
  float mean = meanp[r], rstd = rstdp[r];
  float v0 = (xT[(size_t)r*L_ + t]       - mean)*rstd;
  float v1 = (xT[(size_t)r*L_ + 256 + t] - mean)*rstd;
  xn[t] = v0; xn[t+256] = v1;
  if(t==255){
    #pragma unroll
    for(int i=512;i<520;i++) xn[i]=v1;   // edge pad
  }
  int d0 = (t & 63)*2;
  int p0 = t >> 6;
  float2 w[16];
  #pragma unroll
  for(int j=0;j<16;j++) w[j] = *(const float2*)(Wval + j*128 + d0);
  __syncthreads();

  for(int p=p0;p<64;p+=4){
    const float4* xp = (const float4*)(xn + p*8);
    float4 x0=xp[0], x1=xp[1], x2=xp[2], x3=xp[3];
    float xv[16];
    *(float4*)(xv+0)=x0; *(float4*)(xv+4)=x1; *(float4*)(xv+8)=x2; *(float4*)(xv+12)=x3;
    float2 pw = *(const float2*)(pe + p*128 + d0);
    float a0 = pw.x, a1 = pw.y;
    #pragma unroll
    for(int j=0;j<16;j++){ a0 += xv[j]*w[j].x; a1 += xv[j]*w[j].y; }
    u32 packed = (u32)f2bf(a0) | ((u32)f2bf(a1)<<16);
    *(u32*)(tglob + ((size_t)(r*64+p)*128 + d0)) = packed;
  }
}

// fp64 gating logits (flip-resistant selection); fp32 softmax/lse; per-block
// partials to pg/pi (NO global atomics).
__global__ __launch_bounds__(256) void k_gate(
    const float* __restrict__ xT, const double* __restrict__ meand, const double* __restrict__ rstdd,
    const double* __restrict__ Wvg, const double* __restrict__ peg,
    int* __restrict__ topip, float2* __restrict__ gatep,
    float* __restrict__ pg, int* __restrict__ pib)
{
  __shared__ double xn[520];
  __shared__ double lgt[64][9];
  int r = blockIdx.x, t = threadIdx.x;
  double m = meand[r], rs = rstdd[r];
  double v0 = ((double)xT[(size_t)r*L_ + t]       - m)*rs;
  double v1 = ((double)xT[(size_t)r*L_ + 256 + t] - m)*rs;
  xn[t]=v0; xn[t+256]=v1;
  if(t==255){
    #pragma unroll
    for(int i=512;i<520;i++) xn[i]=v1;
  }
  __syncthreads();
  for(int q=t;q<512;q+=256){
    int p = q>>3, e = q&7;
    double acc = peg[q];
    #pragma unroll
    for(int j=0;j<16;j++) acc += xn[p*8+j]*Wvg[j*8+e];
    lgt[p][e] = acc;
  }
  __syncthreads();
  if(t<64){
    int token = r*64 + t;
    double l0[8];
    #pragma unroll
    for(int e=0;e<8;e++) l0[e]=lgt[t][e];
    double mx=l0[0];
    #pragma unroll
    for(int e=1;e<8;e++) mx = fmax(mx,l0[e]);
    int i1=0; double b1v=l0[0];
    #pragma unroll
    for(int e=1;e<8;e++) if(l0[e]>b1v){b1v=l0[e]; i1=e;}
    int i2=-1; double b2v=-1e300;
    #pragma unroll
    for(int e=0;e<8;e++) if(e!=i1 && l0[e]>b2v){b2v=l0[e]; i2=e;}
    float pr[8]; float sum=0.f;
    #pragma unroll
    for(int e=0;e<8;e++){ pr[e]=__expf((float)(l0[e]-mx)); sum+=pr[e]; }
    float inv = 1.f/sum;
    #pragma unroll
    for(int e=0;e<8;e++) pr[e]*=inv;
    topip[token] = i1 | (i2<<8);
    gatep[token] = make_float2(pr[i1], pr[i2]);
    float lse = (float)mx + __logf(sum);
    // wave-0 reductions, lane0 stores partials
    #pragma unroll
    for(int e=0;e<8;e++){
      float v = pr[e];
      for(int o=32;o>0;o>>=1) v += __shfl_down(v,o);
      if(t==0) pg[r*12+e] = v;
    }
    {
      float z = lse*lse;
      for(int o=32;o>0;o>>=1) z += __shfl_down(z,o);
      if(t==0) pg[r*12+8] = z;
    }
    #pragma unroll
    for(int e=0;e<8;e++){
      u64 m1 = __ballot(i1==e);
      u64 m2 = __ballot(i2==e);
      if(t==0){
        pib[r*16+e]   = (int)__popcll(m1);
        pib[r*16+8+e] = (int)__popcll(m2);
      }
    }
  }
}

// reduce per-block partials; compute aux + bucket starts
__global__ __launch_bounds__(256) void k_aux(const float* __restrict__ pg, const int* __restrict__ pib,
                                             int* __restrict__ ci, float* __restrict__ dout){
  __shared__ double sd[256];
  __shared__ int si[256];
  __shared__ double totd[9];
  __shared__ int toti[16];
  int t = threadIdx.x;
  double accd[9]; int acci[16];
  #pragma unroll
  for(int c=0;c<9;c++) accd[c]=0.0;
  #pragma unroll
  for(int c=0;c<16;c++) acci[c]=0;
  for(int r=t;r<NRW;r+=256){
    #pragma unroll
    for(int c=0;c<9;c++) accd[c] += (double)pg[r*12+c];
    #pragma unroll
    for(int c=0;c<16;c++) acci[c] += pib[r*16+c];
  }
  for(int c=0;c<9;c++){
    sd[t]=accd[c]; __syncthreads();
    for(int o=128;o>0;o>>=1){ if(t<o) sd[t]+=sd[t+o]; __syncthreads(); }
    if(t==0) totd[c]=sd[0];
    __syncthreads();
  }
  for(int c=0;c<16;c++){
    si[t]=acci[c]; __syncthreads();
    for(int o=128;o>0;o>>=1){ if(t<o) si[t]+=si[t+o]; __syncthreads(); }
    if(t==0) toti[c]=si[0];
    __syncthreads();
  }
  if(t==0){
    const double invN = 1.0/(double)NTOK;
    double bal = 0.0;
    int es1=0, bs1=0, es2=0, bs2=0;
    for(int e=0;e<8;e++){
      int c1 = toti[e], c2 = toti[8+e];
      bal += (totd[e]*invN) * ((double)(c1+c2) * invN * 0.5);
      ci[32+e]=es1; ci[16+e]=es1; ci[50+e]=bs1;
      ci[41+e]=es2; ci[24+e]=es2; ci[59+e]=bs2;
      es1 += c1; bs1 += (c1+127)>>7;
      es2 += c2; bs2 += (c2+127)>>7;
    }
    ci[40]=es1; ci[58]=bs1;
    ci[49]=es2; ci[67]=bs2;
    dout[493056] = (float)(0.01*8.0*bal + 0.001*(totd[8]*invN));
  }
}

__global__ __launch_bounds__(256) void k_scatter(const int* __restrict__ topip,
    const float2* __restrict__ gatep, int* __restrict__ ci,
    int* __restrict__ btok, float* __restrict__ bgt){
  __shared__ int lc[16]; __shared__ int lb[16];
  int t = threadIdx.x;
  int token = blockIdx.x*256 + t;
  if(t<16) lc[t]=0;
  __syncthreads();
  int ti = topip[token];
  float2 g = gatep[token];
  int e1 = ti & 255, e2 = (ti>>8)&255;
  int r1 = atomicAdd(&lc[e1],1);
  int r2 = atomicAdd(&lc[8+e2],1);
  __syncthreads();
  if(t<8)            lb[t] = atomicAdd(&ci[16+t],   lc[t]);
  else if(t<16)      lb[t] = atomicAdd(&ci[24+t-8], lc[t]);
  __syncthreads();
  int p1 = lb[e1]+r1, p2 = lb[8+e2]+r2;
  btok[p1] = token;         bgt[p1] = g.x;
  btok[NBUCK+p2] = token;   bgt[NBUCK+p2] = g.y;
}

// fused per-expert FFN, one slot per pass.
__global__ __launch_bounds__(256,2) void k_expert(
    const u16* __restrict__ tglob,
    const u16* __restrict__ W1T, const u16* __restrict__ W2T,
    const float* __restrict__ b1g, const float* __restrict__ b2g,
    const int* __restrict__ ci,
    const int* __restrict__ btok, const float* __restrict__ bgt,
    u16* __restrict__ outg, int slot)
{
  __shared__ __align__(16) u16 As[128*128];   // 32 KB
  __shared__ __align__(16) u16 Ws[128*64];    // 16 KB
  __shared__ __align__(16) u16 Ss[128*64];    // 16 KB  (total 64 KB)

  int bid = blockIdx.x, t = threadIdx.x;
  int stB = 32 + slot*9, bsB = 50 + slot*9;
  int boff = slot*NBUCK;
  int totalB = ci[bsB+8];
  if(bid >= totalB) return;
  int e = 0;
  #pragma unroll
  for(int k2=1;k2<8;k2++) if(bid >= ci[bsB+k2]) e = k2;
  int row0 = ci[stB+e] + (bid - ci[bsB+e])*128;
  int rend = ci[stB+e+1];

  if(t<128){
    int pos = row0+t;
    ((int*)Ws)[t] = (pos<rend) ? btok[boff+pos] : -1;
  }
  __syncthreads();
  { // gather A rows from token buffer
    int lr = t>>1, half = t&1;
    int token = ((int*)Ws)[lr];
    int tk = (token>=0) ? token : 0;
    const u16* src = tglob + (size_t)tk*128 + half*64;
    #pragma unroll
    for(int i=0;i<8;i++){
      int kb = half*8 + i;
      uint4 v = *(const uint4*)(src + i*8);
      *(uint4*)(As + lr*128 + ((kb ^ swz(lr))<<3)) = v;
    }
  }
  __syncthreads();

  int wid = t>>6, lane = t&63;
  int wr = wid>>1, wc = wid&1;
  int quad = lane>>4, li = lane&15;

  f32x4 accO[4][4];
  #pragma unroll
  for(int i=0;i<4;i++)
    #pragma unroll
    for(int j=0;j<4;j++) accO[i][j] = (f32x4){0.f,0.f,0.f,0.f};

  float myb2[4];
  #pragma unroll
  for(int nt=0;nt<4;nt++) myb2[nt] = b2g[e*128 + wc*64 + nt*16 + li];

  for(int hc=0;hc<8;hc++){
    { // stage W1 chunk [64h][128d]
      int hr = t>>2, qq = t&3;
      const u16* src = W1T + ((size_t)e*H_ + hc*64 + hr)*128 + qq*32;
      #pragma unroll
      for(int i=0;i<4;i++){
        int kb = qq*4 + i;
        uint4 v = *(const uint4*)(src + i*8);
        *(uint4*)(Ws + hr*128 + ((kb ^ (hr&7))<<3)) = v;
      }
    }
    __syncthreads();
    // GEMM1: S(128x64) = A(128x128) @ W1c
    f32x4 acc1[4][2];
    #pragma unroll
    for(int i=0;i<4;i++){ acc1[i][0]=(f32x4){0,0,0,0}; acc1[i][1]=(f32x4){0,0,0,0}; }
    #pragma unroll
    for(int ks=0;ks<4;ks++){
      bf16x8 af[4], bfg[2];
      int kb = ks*4 + quad;
      #pragma unroll
      for(int mt=0;mt<4;mt++){
        int row = wr*64 + mt*16 + li;
        af[mt] = *(const bf16x8*)(As + row*128 + ((kb ^ swz(row))<<3));
      }
      #pragma unroll
      for(int nt=0;nt<2;nt++){
        int hrow = wc*32 + nt*16 + li;
        bfg[nt] = *(const bf16x8*)(Ws + hrow*128 + ((kb ^ (hrow&7))<<3));
      }
      #pragma unroll
      for(int mt=0;mt<4;mt++)
        #pragma unroll
        for(int nt=0;nt<2;nt++)
          acc1[mt][nt] = MFMA16(af[mt], bfg[nt], acc1[mt][nt]);
    }
    float b1v[2];
    #pragma unroll
    for(int nt=0;nt<2;nt++) b1v[nt] = b1g[e*H_ + hc*64 + wc*32 + nt*16 + li];
    #pragma unroll
    for(int mt=0;mt<4;mt++)
      #pragma unroll
      for(int nt=0;nt<2;nt++)
        #pragma unroll
        for(int rg=0;rg<4;rg++){
          int row = wr*64 + mt*16 + quad*4 + rg;
          int d   = wc*32 + nt*16 + li;
          float g = gelu_f(acc1[mt][nt][rg] + b1v[nt]);
          Ss[row*64 + (((d>>3) ^ swz(row))<<3) + (d&7)] = f2bf(g);
        }
    __syncthreads();
    { // stage W2 chunk [128d][64h]
      int dr = t>>1, hh = t&1;
      const u16* src = W2T + ((size_t)e*D_ + dr)*H_ + hc*64 + hh*32;
      #pragma unroll
      for(int i=0;i<4;i++){
        int kb = hh*4 + i;
        uint4 v = *(const uint4*)(src + i*8);
        *(uint4*)(Ws + dr*64 + ((kb ^ (dr&7))<<3)) = v;
      }
    }
    __syncthreads();
    // GEMM2: accO += S(128x64) @ W2c
    #pragma unroll
    for(int ks=0;ks<2;ks++){
      bf16x8 af[4], bfg[4];
      int kb = ks*4 + quad;
      #pragma unroll
      for(int mt=0;mt<4;mt++){
        int row = wr*64 + mt*16 + li;
        af[mt] = *(const bf16x8*)(Ss + row*64 + ((kb ^ swz(row))<<3));
      }
      #pragma unroll
      for(int nt=0;nt<4;nt++){
        int drow = wc*64 + nt*16 + li;
        bfg[nt] = *(const bf16x8*)(Ws + drow*64 + ((kb ^ (drow&7))<<3));
      }
      #pragma unroll
      for(int mt=0;mt<4;mt++)
        #pragma unroll
        for(int nt=0;nt<4;nt++)
          accO[mt][nt] = MFMA16(af[mt], bfg[nt], accO[mt][nt]);
    }
    __syncthreads();
  }

  // epilogue: reload token/gate, scale, transpose via As, coalesced (RMW) store
  if(t<128){
    int pos = row0+t;
    bool v = pos<rend;
    ((float*)Ss)[t]   = v ? bgt[boff+pos]  : 0.f;
    ((int*)Ss)[128+t] = v ? btok[boff+pos] : -1;
  }
  __syncthreads();
  #pragma unroll
  for(int mt=0;mt<4;mt++)
    #pragma unroll
    for(int nt=0;nt<4;nt++)
      #pragma unroll
      for(int rg=0;rg<4;rg++){
        int row = wr*64 + mt*16 + quad*4 + rg;
        int d   = wc*64 + nt*16 + li;
        float v = (accO[mt][nt][rg] + myb2[nt]) * ((float*)Ss)[row];
        As[row*128 + (((d>>3) ^ swz(row))<<3) + (d&7)] = f2bf(v);
      }
  __syncthreads();
  {
    int lr = t>>1, half = t&1;
    int token = ((int*)Ss)[128+lr];
    if(token>=0){
      u16* dst = outg + (size_t)token*128 + half*64;
      #pragma unroll
      for(int i=0;i<8;i++){
        int kb = half*8 + i;
        uint4 v = *(const uint4*)(As + lr*128 + ((kb ^ swz(lr))<<3));
        if(slot==1){
          uint4 o = *(const uint4*)(dst + i*8);
          v.x = bfadd2(v.x, o.x); v.y = bfadd2(v.y, o.y);
          v.z = bfadd2(v.z, o.z); v.w = bfadd2(v.w, o.w);
        }
        *(uint4*)(dst + i*8) = v;
      }
    }
  }
}

// OUT[r*64+p][d] -> Ahead[r][d*64+p]  (bf16 transpose per row-block)
__global__ __launch_bounds__(256) void k_trans(const u16* __restrict__ outg, u16* __restrict__ Ahead){
  __shared__ u16 s[64][136];
  int r = blockIdx.x, t = threadIdx.x;
  {
    int p = t>>2, dc = (t&3)*32;
    const u16* src = outg + ((size_t)(r*64+p))*128 + dc;
    #pragma unroll
    for(int i=0;i<4;i++){
      uint4 v = *(const uint4*)(src + i*8);
      *(uint4*)(&s[p][dc + i*8]) = v;
    }
  }
  __syncthreads();
  {
    int d = t>>1, pr = (t&1)*32;
    u32 wbuf[16];
    #pragma unroll
    for(int i=0;i<16;i++){
      u32 lo = s[pr + 2*i    ][d];
      u32 hi = s[pr + 2*i + 1][d];
      wbuf[i] = lo | (hi<<16);
    }
    u16* dst = Ahead + (size_t)r*DP_ + d*64 + pr;
    #pragma unroll
    for(int i=0;i<4;i++) *(uint4*)(dst + i*8) = *(uint4*)(wbuf + i*4);
  }
}

// head GEMM: dec4[kseg][r][o] = A[r][kseg]@WhT[o][kseg]  (plain stores, no atomics)
__global__ __launch_bounds__(256) void k_head(const u16* __restrict__ Ahead,
    const u16* __restrict__ WhT, float* __restrict__ dec4){
  __shared__ float red[64*96];
  int bid = blockIdx.x;
  int mb = bid>>2, kseg = bid&3;
  int r0 = mb*64;
  int t = threadIdx.x, wid = t>>6, lane = t&63;
  int quad = lane>>4, li = lane&15;
  for(int i=t;i<6144;i+=256) red[i]=0.f;
  __syncthreads();
  size_t kbase = (size_t)kseg*2048 + (size_t)wid*512;
  f32x4 acc[4][6];
  #pragma unroll
  for(int i=0;i<4;i++)
    #pragma unroll
    for(int j=0;j<6;j++) acc[i][j]=(f32x4){0,0,0,0};
  bf16x8 zf = {0,0,0,0,0,0,0,0};
  for(int ks=0;ks<16;ks++){
    size_t k = kbase + ks*32 + quad*8;
    bf16x8 af[4], bfg[6];
    #pragma unroll
    for(int mt=0;mt<4;mt++){
      int row = r0 + mt*16 + li;
      af[mt] = (row<NRW) ? *(const bf16x8*)(Ahead + (size_t)row*DP_ + k) : zf;
    }
    #pragma unroll
    for(int nt=0;nt<6;nt++){
      int n = nt*16 + li;
      bfg[nt] = *(const bf16x8*)(WhT + (size_t)n*DP_ + k);
    }
    #pragma unroll
    for(int mt=0;mt<4;mt++)
      #pragma unroll
      for(int nt=0;nt<6;nt++)
        acc[mt][nt] = MFMA16(af[mt], bfg[nt], acc[mt][nt]);
  }
  #pragma unroll
  for(int mt=0;mt<4;mt++)
    #pragma unroll
    for(int nt=0;nt<6;nt++)
      #pragma unroll
      for(int rg=0;rg<4;rg++){
        int m = mt*16 + quad*4 + rg;
        int n = nt*16 + li;
        atomicAdd(&red[m*96+n], acc[mt][nt][rg]);   // LDS atomic (ds_add_f32)
      }
  __syncthreads();
  float* dst = dec4 + (size_t)kseg*NRW*96;
  for(int i=t;i<6144;i+=256){
    int m = i/96, n = i - m*96;
    if(r0+m < NRW) dst[(size_t)(r0+m)*96 + n] = red[i];
  }
}

// sum 4 k-segments + transpose + bias + denorm
__global__ void k_final(const float* __restrict__ dec4, const float* __restrict__ bhead,
    const float* __restrict__ stdp, const float* __restrict__ meanp, float* __restrict__ outp){
  __shared__ float s[64*97];
  int b = blockIdx.y, v0 = blockIdx.x*64;
  int t = threadIdx.x;
  for(int i=t;i<6144;i+=256){
    int vi = i/96, o = i - vi*96;
    int v = v0+vi;
    float acc = 0.f;
    if(v<NV_){
      size_t base = (size_t)(b*NV_+v)*96 + o;
      #pragma unroll
      for(int ks=0;ks<4;ks++) acc += dec4[(size_t)ks*NRW*96 + base];
    }
    s[vi*97+o] = acc;
  }
  __syncthreads();
  for(int i=t;i<6144;i+=256){
    int o = i>>6, vi = i&63;
    int v = v0+vi;
    if(v<NV_){
      int r = b*NV_+v;
      outp[((size_t)b*96 + o)*NV_ + v] = (s[vi*97+o] + bhead[o])*stdp[r] + meanp[r];
    }
  }
}

// ============ launcher ============
extern "C" void kernel_launch(void* const* d_in, const int* in_sizes, int n_in,
                              void* d_out, int out_size, void* d_ws, size_t ws_size,
                              hipStream_t stream){
  const float* x_enc = (const float*)d_in[0];
  const float* W_val = (const float*)d_in[4];
  const float* W_g   = (const float*)d_in[5];
  const float* W1    = (const float*)d_in[6];
  const float* b1    = (const float*)d_in[7];
  const float* W2    = (const float*)d_in[8];
  const float* b2    = (const float*)d_in[9];
  const float* W_head= (const float*)d_in[10];
  const float* b_head= (const float*)d_in[11];
  float* outp = (float*)d_out;
  char* ws = (char*)d_ws;

  float* meanp = (float*)(ws+OFF_MEAN);
  float* rstdp = (float*)(ws+OFF_RSTD);
  float* stdp  = (float*)(ws+OFF_STD);
  float* xT    = (float*)(ws+OFF_XT);
  float* dec4  = (float*)(ws+OFF_XT);   // aliases xT (dead after k_gate)
  float* pe    = (float*)(ws+OFF_PE);
  u16*   W1T   = (u16*)(ws+OFF_W1T);
  u16*   W2T   = (u16*)(ws+OFF_W2T);
  u16*   WhT   = (u16*)(ws+OFF_WHT);
  u16*   tglob = (u16*)(ws+OFF_T);
  u16*   Ahead = (u16*)(ws+OFF_T);      // aliases token buffer (dead after expert passes)
  int*   topip = (int*)(ws+OFF_TOPI);
  float2* gatep= (float2*)(ws+OFF_GATE);
  int*   ci    = (int*)(ws+OFF_CNTR+128);
  int*   btok  = (int*)(ws+OFF_BTOK);
  float* bgt   = (float*)(ws+OFF_BGT);
  u16*   outg  = (u16*)(ws+OFF_OUT);
  double* meand= (double*)(ws+OFF_MEAND);
  double* rstdd= (double*)(ws+OFF_RSTDD);
  double* ped  = (double*)(ws+OFF_PED);
  double* Wvg  = (double*)(ws+OFF_WVG);
  double* peg  = (double*)(ws+OFF_PEG);
  float* pg    = (float*)(ws+OFF_PG);
  int*   pib   = (int*)(ws+OFF_PI);

  hipMemsetAsync(ws+OFF_CNTR, 0, 1024, stream);

  k_xt<<<dim3(11,16,B_), dim3(32,8), 0, stream>>>(x_enc, xT);
  k_stats<<<NRW, 256, 0, stream>>>(xT, meanp, rstdp, stdp, meand, rstdd);
  k_pe<<<32, 256, 0, stream>>>(pe, ped);
  k_prep<<<1, 256, 0, stream>>>(W_val, W_g, ped, Wvg, peg);
  k_wt<<<dim3(16,4,E_), dim3(32,8), 0, stream>>>(W1, W1T, 128, 512);
  k_wt<<<dim3(4,16,E_), dim3(32,8), 0, stream>>>(W2, W2T, 512, 128);
  k_wt<<<dim3(3,256,1), dim3(32,8), 0, stream>>>(W_head, WhT, 8192, 96);
  k_embed<<<NRW, 256, 0, stream>>>(xT, meanp, rstdp, W_val, pe, tglob);
  k_gate<<<NRW, 256, 0, stream>>>(xT, meand, rstdd, Wvg, peg, topip, gatep, pg, pib);
  k_aux<<<1, 256, 0, stream>>>(pg, pib, ci, outp);
  k_scatter<<<NTOK/256, 256, 0, stream>>>(topip, gatep, ci, btok, bgt);
  k_expert<<<2576, 256, 0, stream>>>(tglob, W1T, W2T, b1, b2, ci, btok, bgt, outg, 0);
  k_expert<<<2576, 256, 0, stream>>>(tglob, W1T, W2T, b1, b2, ci, btok, bgt, outg, 1);
  k_trans<<<NRW, 256, 0, stream>>>(outg, Ahead);
  k_head<<<324, 256, 0, stream>>>(Ahead, WhT, dec4);
  k_final<<<dim3(6,B_), 256, 0, stream>>>(dec4, b_head, stdp, meanp, outp);
}

// Round 5
// 776.628 us; speedup vs baseline: 2.5643x; 1.0801x over previous
//
#include <hip/hip_runtime.h>
#include <hip/hip_bf16.h>

typedef unsigned short u16;
typedef unsigned int   u32;
typedef unsigned long long u64;
typedef __attribute__((ext_vector_type(8))) short bf16x8;
typedef __attribute__((ext_vector_type(4))) float f32x4;

#define MFMA16(a,b,c) __builtin_amdgcn_mfma_f32_16x16x32_bf16(a,b,c,0,0,0)

// ---- problem dims ----
#define NV_   321
#define B_    16
#define L_    512
#define D_    128
#define P_    64
#define E_    8
#define H_    512
#define NRW   5136        // B*NV
#define NTOK  328704      // NRW*P
#define DP_   8192        // D*P
#define NBUCK 329728      // NTOK + 8*128 padding

static __device__ __forceinline__ u16 f2bf(float f){
  __hip_bfloat16 h = __float2bfloat16(f);
  return *reinterpret_cast<u16*>(&h);
}

// sigma-form tanh-GELU: x*sigma(1.5958x(1+0.044715x^2)) == 0.5x(1+tanh(u)).
// p = c1 + c2*x^2 folds the -log2(e) scale so exp2f maps straight to v_exp_f32.
static __device__ __forceinline__ float gelu_f(float x){
  float x2 = x*x;
  float p  = __builtin_fmaf(-0.1029433f, x2, -2.3022083f);
  float a  = x*p;                       // = -2u*log2(e)
  float en = exp2f(a);                  // e^{-2u}
  float r  = __builtin_amdgcn_rcpf(1.0f + en);
  return x*r;
}

static __device__ __forceinline__ u32 bfadd2(u32 a, u32 b){
  float lo = __uint_as_float(a<<16)           + __uint_as_float(b<<16);
  float hi = __uint_as_float(a&0xffff0000u)   + __uint_as_float(b&0xffff0000u);
  return (u32)f2bf(lo) | ((u32)f2bf(hi)<<16);
}

// swizzle for 128B-period LDS rows (As only)
static __device__ __forceinline__ int swz(int r){ return (r ^ (r>>3)) & 7; }

// ============ workspace layout (bytes) ============
static constexpr size_t alup(size_t x){ return (x + 255) & ~(size_t)255; }
static constexpr size_t OFF_MEAN = 0;
static constexpr size_t OFF_RSTD = OFF_MEAN + alup((size_t)NRW*4);
static constexpr size_t OFF_STD  = OFF_RSTD + alup((size_t)NRW*4);
static constexpr size_t OFF_XT   = OFF_STD  + alup((size_t)NRW*4);
static constexpr size_t OFF_PE   = OFF_XT   + alup((size_t)NRW*L_*4);
static constexpr size_t OFF_W1T  = OFF_PE   + alup((size_t)P_*D_*4);
static constexpr size_t OFF_W2T  = OFF_W1T  + alup((size_t)E_*H_*D_*2);
static constexpr size_t OFF_WHT  = OFF_W2T  + alup((size_t)E_*D_*H_*2);
static constexpr size_t OFF_T    = OFF_WHT  + alup((size_t)96*DP_*2);      // tokens bf16; later ALIASED as Ahead
static constexpr size_t OFF_TOPI = OFF_T    + alup((size_t)NTOK*D_*2);
static constexpr size_t OFF_GATE = OFF_TOPI + alup((size_t)NTOK*4);
static constexpr size_t OFF_CNTR = OFF_GATE + alup((size_t)NTOK*8);
static constexpr size_t OFF_BTOK = OFF_CNTR + alup((size_t)1024);
static constexpr size_t OFF_BGT  = OFF_BTOK + alup((size_t)2*NBUCK*4);
static constexpr size_t OFF_OUT  = OFF_BGT  + alup((size_t)2*NBUCK*4);     // token outputs bf16; later ALIASED as dec8 (16MB)
static constexpr size_t OFF_DEC  = OFF_OUT  + alup((size_t)NTOK*D_*2);
static constexpr size_t OFF_MEAND= OFF_DEC  + alup((size_t)NRW*96*4);
static constexpr size_t OFF_RSTDD= OFF_MEAND+ alup((size_t)NRW*8);
static constexpr size_t OFF_PED  = OFF_RSTDD+ alup((size_t)NRW*8);
static constexpr size_t OFF_WVG  = OFF_PED  + alup((size_t)P_*D_*8);
static constexpr size_t OFF_PEG  = OFF_WVG  + alup((size_t)16*8*8);
static constexpr size_t OFF_PG   = OFF_PEG  + alup((size_t)P_*E_*8);
static constexpr size_t OFF_PI   = OFF_PG   + alup((size_t)NRW*12*4);
// end = OFF_PI + NRW*64  ~= 195 MB

// ci ints at OFF_CNTR+128: [16..23]=cur1 [24..31]=cur2
// [32..40]=start1 [41..49]=start2 [50..58]=bstart1 [59..67]=bstart2

// ============ kernels ============

__global__ void k_xt(const float* __restrict__ x, float* __restrict__ xT){
  __shared__ float tile[32][33];
  int b = blockIdx.z;
  int v0 = blockIdx.x*32, l0 = blockIdx.y*32;
  int tx = threadIdx.x, ty = threadIdx.y;
  for(int i=ty;i<32;i+=8){
    int l = l0+i, v = v0+tx;
    tile[i][tx] = (v<NV_) ? x[((size_t)b*L_ + l)*NV_ + v] : 0.f;
  }
  __syncthreads();
  for(int i=ty;i<32;i+=8){
    int v = v0+i, l = l0+tx;
    if(v<NV_) xT[((size_t)(b*NV_+v))*L_ + l] = tile[tx][i];
  }
}

__global__ void k_stats(const float* __restrict__ xT, float* meanp, float* rstdp, float* stdp,
                        double* meand, double* rstdd){
  __shared__ double s1[256], s2[256];
  int r = blockIdx.x, t = threadIdx.x;
  double a = (double)xT[(size_t)r*L_ + t], b = (double)xT[(size_t)r*L_ + 256 + t];
  s1[t]=a+b; s2[t]=a*a+b*b;
  __syncthreads();
  for(int o=128;o>0;o>>=1){ if(t<o){ s1[t]+=s1[t+o]; s2[t]+=s2[t+o]; } __syncthreads(); }
  if(t==0){
    double m = s1[0]*(1.0/512.0);
    double var = s2[0]*(1.0/512.0) - m*m;
    double sd = sqrt(var + 1e-5);
    meanp[r]=(float)m; stdp[r]=(float)sd; rstdp[r]=(float)(1.0/sd);
    meand[r]=m; rstdd[r]=1.0/sd;
  }
}

__global__ void k_pe(float* pef, double* ped){
  int i = blockIdx.x*256 + threadIdx.x;   // 8192
  int p = i>>7, d = i&127;
  int k = d>>1;
  double div = exp(-(double)(2*k) * (9.210340371976184 /128.0)); // ln(10000)/128
  double ang = (double)p * div;
  double v = (d&1) ? cos(ang) : sin(ang);
  float vf = (float)v;
  pef[i] = vf;
  ped[i] = (double)vf;
}

__global__ void k_prep(const float* __restrict__ Wval, const float* __restrict__ Wg,
                       const double* __restrict__ ped, double* __restrict__ Wvg,
                       double* __restrict__ peg){
  int t = threadIdx.x;
  if(t<128){
    int j = t>>3, e = t&7;
    double acc = 0.0;
    for(int d=0;d<128;d++) acc += (double)Wval[j*128+d] * (double)Wg[d*8+e];
    Wvg[t] = acc;
  }
  for(int q=t;q<512;q+=256){
    int p = q>>3, e = q&7;
    double acc = 0.0;
    for(int d=0;d<128;d++) acc += ped[p*128+d] * (double)Wg[d*8+e];
    peg[q] = acc;
  }
}

__global__ void k_wt(const float* __restrict__ in, u16* __restrict__ outp, int R, int C){
  __shared__ float tile[32][33];
  int e = blockIdx.z;
  int c0 = blockIdx.x*32, r0 = blockIdx.y*32;
  const float* src = in + (size_t)e*R*C;
  u16* dst = outp + (size_t)e*R*C;
  int tx=threadIdx.x, ty=threadIdx.y;
  for(int i=ty;i<32;i+=8){
    int r=r0+i, c=c0+tx;
    tile[i][tx] = (r<R && c<C) ? src[(size_t)r*C+c] : 0.f;
  }
  __syncthreads();
  for(int i=ty;i<32;i+=8){
    int c=c0+i, r=r0+tx;
    if(c<C && r<R) dst[(size_t)c*R + r] = f2bf(tile[tx][i]);
  }
}

__global__ __launch_bounds__(256) void k_embed(
    const float* __restrict__ xT, const float* __restrict__ meanp, const float* __restrict__ rstdp,
    const float* __restrict__ Wval, const float* __restrict__ pe,
    u16* __restrict__ tglob)
{
  __shared__ __align__(16) float xn[520];
  int r = blockIdx.x, t = threadIdx.x;
  float mean = meanp[r], rstd = rstdp[r];
  float v0 = (xT[(size_t)r*L_ + t]       - mean)*rstd;
  float v1 = (xT[(size_t)r*L_ + 256 + t] - mean)*rstd;
  xn[t] = v0; xn[t+256] = v1;
  if(t==255){
    #pragma unroll
    for(int i=512;i<520;i++) xn[i]=v1;   // edge pad
  }
  int d0 = (t & 63)*2;
  int p0 = t >> 6;
  float2 w[16];
  #pragma unroll
  for(int j=0;j<16;j++) w[j] = *(const float2*)(Wval + j*128 + d0);
  __syncthreads();

  for(int p=p0;p<64;p+=4){
    const float4* xp = (const float4*)(xn + p*8);
    float4 x0=xp[0], x1=xp[1], x2=xp[2], x3=xp[3];
    float xv[16];
    *(float4*)(xv+0)=x0; *(float4*)(xv+4)=x1; *(float4*)(xv+8)=x2; *(float4*)(xv+12)=x3;
    float2 pw = *(const float2*)(pe + p*128 + d0);
    float a0 = pw.x, a1 = pw.y;
    #pragma unroll
    for(int j=0;j<16;j++){ a0 += xv[j]*w[j].x; a1 += xv[j]*w[j].y; }
    u32 packed = (u32)f2bf(a0) | ((u32)f2bf(a1)<<16);
    *(u32*)(tglob + ((size_t)(r*64+p)*128 + d0)) = packed;
  }
}

__global__ __launch_bounds__(256) void k_gate(
    const float* __restrict__ xT, const double* __restrict__ meand, const double* __restrict__ rstdd,
    const double* __restrict__ Wvg, const double* __restrict__ peg,
    int* __restrict__ topip, float2* __restrict__ gatep,
    float* __restrict__ pg, int* __restrict__ pib)
{
  __shared__ double xn[520];
  __shared__ double lgt[64][9];
  int r = blockIdx.x, t = threadIdx.x;
  double m = meand[r], rs = rstdd[r];
  double v0 = ((double)xT[(size_t)r*L_ + t]       - m)*rs;
  double v1 = ((double)xT[(size_t)r*L_ + 256 + t] - m)*rs;
  xn[t]=v0; xn[t+256]=v1;
  if(t==255){
    #pragma unroll
    for(int i=512;i<520;i++) xn[i]=v1;
  }
  __syncthreads();
  for(int q=t;q<512;q+=256){
    int p = q>>3, e = q&7;
    double acc = peg[q];
    #pragma unroll
    for(int j=0;j<16;j++) acc += xn[p*8+j]*Wvg[j*8+e];
    lgt[p][e] = acc;
  }
  __syncthreads();
  if(t<64){
    int token = r*64 + t;
    double l0[8];
    #pragma unroll
    for(int e=0;e<8;e++) l0[e]=lgt[t][e];
    double mx=l0[0];
    #pragma unroll
    for(int e=1;e<8;e++) mx = fmax(mx,l0[e]);
    int i1=0; double b1v=l0[0];
    #pragma unroll
    for(int e=1;e<8;e++) if(l0[e]>b1v){b1v=l0[e]; i1=e;}
    int i2=-1; double b2v=-1e300;
    #pragma unroll
    for(int e=0;e<8;e++) if(e!=i1 && l0[e]>b2v){b2v=l0[e]; i2=e;}
    float pr[8]; float sum=0.f;
    #pragma unroll
    for(int e=0;e<8;e++){ pr[e]=__expf((float)(l0[e]-mx)); sum+=pr[e]; }
    float inv = 1.f/sum;
    #pragma unroll
    for(int e=0;e<8;e++) pr[e]*=inv;
    topip[token] = i1 | (i2<<8);
    gatep[token] = make_float2(pr[i1], pr[i2]);
    float lse = (float)mx + __logf(sum);
    #pragma unroll
    for(int e=0;e<8;e++){
      float v = pr[e];
      for(int o=32;o>0;o>>=1) v += __shfl_down(v,o);
      if(t==0) pg[r*12+e] = v;
    }
    {
      float z = lse*lse;
      for(int o=32;o>0;o>>=1) z += __shfl_down(z,o);
      if(t==0) pg[r*12+8] = z;
    }
    #pragma unroll
    for(int e=0;e<8;e++){
      u64 m1 = __ballot(i1==e);
      u64 m2 = __ballot(i2==e);
      if(t==0){
        pib[r*16+e]   = (int)__popcll(m1);
        pib[r*16+8+e] = (int)__popcll(m2);
      }
    }
  }
}

__global__ __launch_bounds__(256) void k_aux(const float* __restrict__ pg, const int* __restrict__ pib,
                                             int* __restrict__ ci, float* __restrict__ dout){
  __shared__ double sd[256];
  __shared__ int si[256];
  __shared__ double totd[9];
  __shared__ int toti[16];
  int t = threadIdx.x;
  double accd[9]; int acci[16];
  #pragma unroll
  for(int c=0;c<9;c++) accd[c]=0.0;
  #pragma unroll
  for(int c=0;c<16;c++) acci[c]=0;
  for(int r=t;r<NRW;r+=256){
    #pragma unroll
    for(int c=0;c<9;c++) accd[c] += (double)pg[r*12+c];
    #pragma unroll
    for(int c=0;c<16;c++) acci[c] += pib[r*16+c];
  }
  for(int c=0;c<9;c++){
    sd[t]=accd[c]; __syncthreads();
    for(int o=128;o>0;o>>=1){ if(t<o) sd[t]+=sd[t+o]; __syncthreads(); }
    if(t==0) totd[c]=sd[0];
    __syncthreads();
  }
  for(int c=0;c<16;c++){
    si[t]=acci[c]; __syncthreads();
    for(int o=128;o>0;o>>=1){ if(t<o) si[t]+=si[t+o]; __syncthreads(); }
    if(t==0) toti[c]=si[0];
    __syncthreads();
  }
  if(t==0){
    const double invN = 1.0/(double)NTOK;
    double bal = 0.0;
    int es1=0, bs1=0, es2=0, bs2=0;
    for(int e=0;e<8;e++){
      int c1 = toti[e], c2 = toti[8+e];
      bal += (totd[e]*invN) * ((double)(c1+c2) * invN * 0.5);
      ci[32+e]=es1; ci[16+e]=es1; ci[50+e]=bs1;
      ci[41+e]=es2; ci[24+e]=es2; ci[59+e]=bs2;
      es1 += c1; bs1 += (c1+127)>>7;
      es2 += c2; bs2 += (c2+127)>>7;
    }
    ci[40]=es1; ci[58]=bs1;
    ci[49]=es2; ci[67]=bs2;
    dout[493056] = (float)(0.01*8.0*bal + 0.001*(totd[8]*invN));
  }
}

__global__ __launch_bounds__(256) void k_scatter(const int* __restrict__ topip,
    const float2* __restrict__ gatep, int* __restrict__ ci,
    int* __restrict__ btok, float* __restrict__ bgt){
  __shared__ int lc[16]; __shared__ int lb[16];
  int t = threadIdx.x;
  int token = blockIdx.x*256 + t;
  if(t<16) lc[t]=0;
  __syncthreads();
  int ti = topip[token];
  float2 g = gatep[token];
  int e1 = ti & 255, e2 = (ti>>8)&255;
  int r1 = atomicAdd(&lc[e1],1);
  int r2 = atomicAdd(&lc[8+e2],1);
  __syncthreads();
  if(t<8)            lb[t] = atomicAdd(&ci[16+t],   lc[t]);
  else if(t<16)      lb[t] = atomicAdd(&ci[24+t-8], lc[t]);
  __syncthreads();
  int p1 = lb[e1]+r1, p2 = lb[8+e2]+r2;
  btok[p1] = token;         bgt[p1] = g.x;
  btok[NBUCK+p2] = token;   bgt[NBUCK+p2] = g.y;
}

// fused per-expert FFN, 32-hidden chunks, padded-stride LDS (affine hot addrs).
// LDS: As 32KB (XOR) + Ws 10KB (W1c[32][136] / W2c[128][40]) + Ss 10KB ([128][40]) = 52KB -> 3 blocks/CU
__global__ __launch_bounds__(256,3) void k_expert(
    const u16* __restrict__ tglob,
    const u16* __restrict__ W1T, const u16* __restrict__ W2T,
    const float* __restrict__ b1g, const float* __restrict__ b2g,
    const int* __restrict__ ci,
    const int* __restrict__ btok, const float* __restrict__ bgt,
    u16* __restrict__ outg, int slot)
{
  __shared__ __align__(16) u16 As[128*128];
  __shared__ __align__(16) u16 Ws[5120];
  __shared__ __align__(16) u16 Ss[5120];

  int bid = blockIdx.x, t = threadIdx.x;
  int stB = 32 + slot*9, bsB = 50 + slot*9;
  int boff = slot*NBUCK;
  if(bid >= ci[bsB+8]) return;
  int e = 0;
  #pragma unroll
  for(int k2=1;k2<8;k2++) if(bid >= ci[bsB+k2]) e = k2;
  int row0 = ci[stB+e] + (bid - ci[bsB+e])*128;
  int rend = ci[stB+e+1];

  if(t<128){
    int pos = row0+t;
    ((int*)Ss)[t] = (pos<rend) ? btok[boff+pos] : -1;
  }
  __syncthreads();
  { // gather A rows (XOR-swizzled 8-u16 groups)
    int lr = t>>1, half = t&1;
    int token = ((int*)Ss)[lr];
    int tk = (token>=0) ? token : 0;
    const u16* src = tglob + (size_t)tk*128 + half*64;
    #pragma unroll
    for(int i=0;i<8;i++){
      int kb = half*8 + i;
      uint4 v = *(const uint4*)(src + i*8);
      *(uint4*)(As + lr*128 + ((kb ^ swz(lr))<<3)) = v;
    }
  }
  // NOTE: first in-loop __syncthreads covers the gather->GEMM1 hazard.

  int wid = t>>6, lane = t&63, quad = lane>>4, li = lane&15;
  int rb = wid*32;                      // wave owns 32 token-rows
  int swz0 = swz(rb+li), swz1 = swz(rb+16+li);

  f32x4 accO[2][8];
  #pragma unroll
  for(int i=0;i<2;i++)
    #pragma unroll
    for(int j=0;j<8;j++) accO[i][j] = (f32x4){0.f,0.f,0.f,0.f};

  for(int hc=0;hc<16;hc++){
    { // stage W1 chunk [32h][128d] -> Ws stride 136
      int hr = t>>3, qq = t&7;
      const u16* src = W1T + ((size_t)e*H_ + hc*32 + hr)*128 + qq*16;
      u16* dst = Ws + hr*136 + qq*16;
      *(uint4*)(dst)   = *(const uint4*)(src);
      *(uint4*)(dst+8) = *(const uint4*)(src+8);
    }
    __syncthreads();
    // GEMM1: S(128x32) = A(128x128) @ W1c
    f32x4 acc1[2][2];
    acc1[0][0]=(f32x4){0,0,0,0}; acc1[0][1]=(f32x4){0,0,0,0};
    acc1[1][0]=(f32x4){0,0,0,0}; acc1[1][1]=(f32x4){0,0,0,0};
    #pragma unroll
    for(int ks=0;ks<4;ks++){
      int kb = ks*4 + quad;
      bf16x8 a0 = *(const bf16x8*)(As + (rb+li)*128    + ((kb^swz0)<<3));
      bf16x8 a1 = *(const bf16x8*)(As + (rb+16+li)*128 + ((kb^swz1)<<3));
      bf16x8 b0 = *(const bf16x8*)(Ws + li*136      + kb*8);
      bf16x8 b1 = *(const bf16x8*)(Ws + (16+li)*136 + kb*8);
      acc1[0][0] = MFMA16(a0,b0,acc1[0][0]);
      acc1[0][1] = MFMA16(a0,b1,acc1[0][1]);
      acc1[1][0] = MFMA16(a1,b0,acc1[1][0]);
      acc1[1][1] = MFMA16(a1,b1,acc1[1][1]);
    }
    float bv0 = b1g[e*H_ + hc*32 + li];
    float bv1 = b1g[e*H_ + hc*32 + 16 + li];
    #pragma unroll
    for(int mt=0;mt<2;mt++)
      #pragma unroll
      for(int rg=0;rg<4;rg++){
        int row = rb + mt*16 + quad*4 + rg;
        Ss[row*40 + li]      = f2bf(gelu_f(acc1[mt][0][rg] + bv0));
        Ss[row*40 + 16 + li] = f2bf(gelu_f(acc1[mt][1][rg] + bv1));
      }
    __syncthreads();
    { // stage W2 chunk [128d][32h] -> Ws stride 40
      int dr = t>>1, hh = t&1;
      const u16* src = W2T + ((size_t)e*D_ + dr)*H_ + hc*32 + hh*16;
      u16* dst = Ws + dr*40 + hh*16;
      *(uint4*)(dst)   = *(const uint4*)(src);
      *(uint4*)(dst+8) = *(const uint4*)(src+8);
    }
    __syncthreads();
    // GEMM2: accO += S(128x32) @ W2c   (K=32, one k-step)
    {
      bf16x8 a0 = *(const bf16x8*)(Ss + (rb+li)*40    + quad*8);
      bf16x8 a1 = *(const bf16x8*)(Ss + (rb+16+li)*40 + quad*8);
      #pragma unroll
      for(int nt=0;nt<8;nt++){
        bf16x8 bw = *(const bf16x8*)(Ws + (nt*16+li)*40 + quad*8);
        accO[0][nt] = MFMA16(a0,bw,accO[0][nt]);
        accO[1][nt] = MFMA16(a1,bw,accO[1][nt]);
      }
    }
    __syncthreads();
  }

  // epilogue: reload token/gate, scale, transpose via As, coalesced (RMW) store
  if(t<128){
    int pos = row0+t;
    bool v = pos<rend;
    ((float*)Ss)[t]   = v ? bgt[boff+pos]  : 0.f;
    ((int*)Ss)[128+t] = v ? btok[boff+pos] : -1;
  }
  __syncthreads();
  float myb2[8];
  #pragma unroll
  for(int nt=0;nt<8;nt++) myb2[nt] = b2g[e*128 + nt*16 + li];
  #pragma unroll
  for(int mt=0;mt<2;mt++)
    #pragma unroll
    for(int rg=0;rg<4;rg++){
      int row = rb + mt*16 + quad*4 + rg;
      float gt = ((float*)Ss)[row];
      int sw = swz(row);
      #pragma unroll
      for(int nt=0;nt<8;nt++){
        int d = nt*16 + li;
        float v = (accO[mt][nt][rg] + myb2[nt]) * gt;
        As[row*128 + (((d>>3) ^ sw)<<3) + (d&7)] = f2bf(v);
      }
    }
  __syncthreads();
  {
    int lr = t>>1, half = t&1;
    int token = ((int*)Ss)[128+lr];
    if(token>=0){
      u16* dst = outg + (size_t)token*128 + half*64;
      #pragma unroll
      for(int i=0;i<8;i++){
        int kb = half*8 + i;
        uint4 v = *(const uint4*)(As + lr*128 + ((kb ^ swz(lr))<<3));
        if(slot==1){
          uint4 o = *(const uint4*)(dst + i*8);
          v.x = bfadd2(v.x, o.x); v.y = bfadd2(v.y, o.y);
          v.z = bfadd2(v.z, o.z); v.w = bfadd2(v.w, o.w);
        }
        *(uint4*)(dst + i*8) = v;
      }
    }
  }
}

// OUT[r*64+p][d] -> Ahead[r][d*64+p]  (bf16 transpose per row-block)
__global__ __launch_bounds__(256) void k_trans(const u16* __restrict__ outg, u16* __restrict__ Ahead){
  __shared__ u16 s[64][136];
  int r = blockIdx.x, t = threadIdx.x;
  {
    int p = t>>2, dc = (t&3)*32;
    const u16* src = outg + ((size_t)(r*64+p))*128 + dc;
    #pragma unroll
    for(int i=0;i<4;i++){
      uint4 v = *(const uint4*)(src + i*8);
      *(uint4*)(&s[p][dc + i*8]) = v;
    }
  }
  __syncthreads();
  {
    int d = t>>1, pr = (t&1)*32;
    u32 wbuf[16];
    #pragma unroll
    for(int i=0;i<16;i++){
      u32 lo = s[pr + 2*i    ][d];
      u32 hi = s[pr + 2*i + 1][d];
      wbuf[i] = lo | (hi<<16);
    }
    u16* dst = Ahead + (size_t)r*DP_ + d*64 + pr;
    #pragma unroll
    for(int i=0;i<4;i++) *(uint4*)(dst + i*8) = *(uint4*)(wbuf + i*4);
  }
}

// head GEMM v2: wave owns 16 rows, 8-way K-split, no LDS, plain stores.
// dec8[kseg][r][o] partial products; k_final sums.
__global__ __launch_bounds__(256) void k_head(const u16* __restrict__ Ahead,
    const u16* __restrict__ WhT, float* __restrict__ dec8){
  int bid = blockIdx.x;                 // 81 mtiles x 8 ksegs
  int mb = bid>>3, kseg = bid&7;
  int t = threadIdx.x, wid = t>>6, lane = t&63;
  int quad = lane>>4, li = lane&15;
  int r0 = mb*64 + wid*16;
  int rowA = r0 + li; if(rowA >= NRW) rowA = NRW-1;   // clamp (row-local in MFMA)
  const u16* aptr = Ahead + (size_t)rowA*DP_ + kseg*1024 + quad*8;
  const u16* bptr = WhT   + (size_t)li*DP_   + kseg*1024 + quad*8;
  f32x4 acc[6];
  #pragma unroll
  for(int j=0;j<6;j++) acc[j]=(f32x4){0,0,0,0};
  #pragma unroll 4
  for(int ks=0;ks<32;ks++){
    bf16x8 af = *(const bf16x8*)(aptr + ks*32);
    #pragma unroll
    for(int nt=0;nt<6;nt++){
      bf16x8 bw = *(const bf16x8*)(bptr + (size_t)nt*16*DP_ + ks*32);
      acc[nt] = MFMA16(af, bw, acc[nt]);
    }
  }
  float* dst = dec8 + (size_t)kseg*NRW*96;
  #pragma unroll
  for(int nt=0;nt<6;nt++)
    #pragma unroll
    for(int rg=0;rg<4;rg++){
      int m = r0 + quad*4 + rg;
      if(m < NRW) dst[(size_t)m*96 + nt*16 + li] = acc[nt][rg];
    }
}

// sum 8 k-segments + transpose + bias + denorm
__global__ void k_final(const float* __restrict__ dec8, const float* __restrict__ bhead,
    const float* __restrict__ stdp, const float* __restrict__ meanp, float* __restrict__ outp){
  __shared__ float s[64*97];
  int b = blockIdx.y, v0 = blockIdx.x*64;
  int t = threadIdx.x;
  for(int i=t;i<6144;i+=256){
    int vi = i/96, o = i - vi*96;
    int v = v0+vi;
    float acc = 0.f;
    if(v<NV_){
      size_t base = (size_t)(b*NV_+v)*96 + o;
      #pragma unroll
      for(int ks=0;ks<8;ks++) acc += dec8[(size_t)ks*NRW*96 + base];
    }
    s[vi*97+o] = acc;
  }
  __syncthreads();
  for(int i=t;i<6144;i+=256){
    int o = i>>6, vi = i&63;
    int v = v0+vi;
    if(v<NV_){
      int r = b*NV_+v;
      outp[((size_t)b*96 + o)*NV_ + v] = (s[vi*97+o] + bhead[o])*stdp[r] + meanp[r];
    }
  }
}

// ============ launcher ============
extern "C" void kernel_launch(void* const* d_in, const int* in_sizes, int n_in,
                              void* d_out, int out_size, void* d_ws, size_t ws_size,
                              hipStream_t stream){
  const float* x_enc = (const float*)d_in[0];
  const float* W_val = (const float*)d_in[4];
  const float* W_g   = (const float*)d_in[5];
  const float* W1    = (const float*)d_in[6];
  const float* b1    = (const float*)d_in[7];
  const float* W2    = (const float*)d_in[8];
  const float* b2    = (const float*)d_in[9];
  const float* W_head= (const float*)d_in[10];
  const float* b_head= (const float*)d_in[11];
  float* outp = (float*)d_out;
  char* ws = (char*)d_ws;

  float* meanp = (float*)(ws+OFF_MEAN);
  float* rstdp = (float*)(ws+OFF_RSTD);
  float* stdp  = (float*)(ws+OFF_STD);
  float* xT    = (float*)(ws+OFF_XT);
  float* pe    = (float*)(ws+OFF_PE);
  u16*   W1T   = (u16*)(ws+OFF_W1T);
  u16*   W2T   = (u16*)(ws+OFF_W2T);
  u16*   WhT   = (u16*)(ws+OFF_WHT);
  u16*   tglob = (u16*)(ws+OFF_T);
  u16*   Ahead = (u16*)(ws+OFF_T);      // aliases token buffer (dead after expert passes)
  int*   topip = (int*)(ws+OFF_TOPI);
  float2* gatep= (float2*)(ws+OFF_GATE);
  int*   ci    = (int*)(ws+OFF_CNTR+128);
  int*   btok  = (int*)(ws+OFF_BTOK);
  float* bgt   = (float*)(ws+OFF_BGT);
  u16*   outg  = (u16*)(ws+OFF_OUT);
  float* dec8  = (float*)(ws+OFF_OUT);  // aliases outg (dead after k_trans)
  double* meand= (double*)(ws+OFF_MEAND);
  double* rstdd= (double*)(ws+OFF_RSTDD);
  double* ped  = (double*)(ws+OFF_PED);
  double* Wvg  = (double*)(ws+OFF_WVG);
  double* peg  = (double*)(ws+OFF_PEG);
  float* pg    = (float*)(ws+OFF_PG);
  int*   pib   = (int*)(ws+OFF_PI);

  hipMemsetAsync(ws+OFF_CNTR, 0, 1024, stream);

  k_xt<<<dim3(11,16,B_), dim3(32,8), 0, stream>>>(x_enc, xT);
  k_stats<<<NRW, 256, 0, stream>>>(xT, meanp, rstdp, stdp, meand, rstdd);
  k_pe<<<32, 256, 0, stream>>>(pe, ped);
  k_prep<<<1, 256, 0, stream>>>(W_val, W_g, ped, Wvg, peg);
  k_wt<<<dim3(16,4,E_), dim3(32,8), 0, stream>>>(W1, W1T, 128, 512);
  k_wt<<<dim3(4,16,E_), dim3(32,8), 0, stream>>>(W2, W2T, 512, 128);
  k_wt<<<dim3(3,256,1), dim3(32,8), 0, stream>>>(W_head, WhT, 8192, 96);
  k_embed<<<NRW, 256, 0, stream>>>(xT, meanp, rstdp, W_val, pe, tglob);
  k_gate<<<NRW, 256, 0, stream>>>(xT, meand, rstdd, Wvg, peg, topip, gatep, pg, pib);
  k_aux<<<1, 256, 0, stream>>>(pg, pib, ci, outp);
  k_scatter<<<NTOK/256, 256, 0, stream>>>(topip, gatep, ci, btok, bgt);
  k_expert<<<2576, 256, 0, stream>>>(tglob, W1T, W2T, b1, b2, ci, btok, bgt, outg, 0);
  k_expert<<<2576, 256, 0, stream>>>(tglob, W1T, W2T, b1, b2, ci, btok, bgt, outg, 1);
  k_trans<<<NRW, 256, 0, stream>>>(outg, Ahead);
  k_head<<<648, 256, 0, stream>>>(Ahead, WhT, dec8);
  k_final<<<dim3(6,B_), 256, 0, stream>>>(dec8, b_head, stdp, meanp, outp);
}

// Round 6
// 748.871 us; speedup vs baseline: 2.6593x; 1.0371x over previous
//
#include <hip/hip_runtime.h>
#include <hip/hip_bf16.h>

typedef unsigned short u16;
typedef unsigned int   u32;
typedef unsigned long long u64;
typedef __attribute__((ext_vector_type(8))) short bf16x8;
typedef __attribute__((ext_vector_type(4))) float f32x4;
typedef __attribute__((ext_vector_type(16))) float f32x16;

#define MFMA16(a,b,c) __builtin_amdgcn_mfma_f32_16x16x32_bf16(a,b,c,0,0,0)
#define MFMA32(a,b,c) __builtin_amdgcn_mfma_f32_32x32x16_bf16(a,b,c,0,0,0)

// ---- problem dims ----
#define NV_   321
#define B_    16
#define L_    512
#define D_    128
#define P_    64
#define E_    8
#define H_    512
#define NRW   5136        // B*NV
#define NTOK  328704      // NRW*P
#define DP_   8192        // D*P
#define NBUCK 329728      // NTOK + 8*128 padding

static __device__ __forceinline__ u16 f2bf(float f){
  __hip_bfloat16 h = __float2bfloat16(f);
  return *reinterpret_cast<u16*>(&h);
}

// sigma-form tanh-GELU: x*sigma(1.5958x(1+0.044715x^2)); exp2 maps to v_exp_f32
static __device__ __forceinline__ float gelu_f(float x){
  float x2 = x*x;
  float p  = __builtin_fmaf(-0.1029433f, x2, -2.3022083f);
  float a  = x*p;
  float en = exp2f(a);
  float r  = __builtin_amdgcn_rcpf(1.0f + en);
  return x*r;
}

static __device__ __forceinline__ u32 bfadd2(u32 a, u32 b){
  float lo = __uint_as_float(a<<16)           + __uint_as_float(b<<16);
  float hi = __uint_as_float(a&0xffff0000u)   + __uint_as_float(b&0xffff0000u);
  return (u32)f2bf(lo) | ((u32)f2bf(hi)<<16);
}

// ============ workspace layout (bytes) ============
static constexpr size_t alup(size_t x){ return (x + 255) & ~(size_t)255; }
static constexpr size_t OFF_MEAN = 0;
static constexpr size_t OFF_RSTD = OFF_MEAN + alup((size_t)NRW*4);
static constexpr size_t OFF_STD  = OFF_RSTD + alup((size_t)NRW*4);
static constexpr size_t OFF_XT   = OFF_STD  + alup((size_t)NRW*4);
static constexpr size_t OFF_PE   = OFF_XT   + alup((size_t)NRW*L_*4);
static constexpr size_t OFF_W1T  = OFF_PE   + alup((size_t)P_*D_*4);
static constexpr size_t OFF_W2T  = OFF_W1T  + alup((size_t)E_*H_*D_*2);
static constexpr size_t OFF_WHT  = OFF_W2T  + alup((size_t)E_*D_*H_*2);
static constexpr size_t OFF_T    = OFF_WHT  + alup((size_t)96*DP_*2);      // tokens bf16; later ALIASED as dec8
static constexpr size_t OFF_TOPI = OFF_T    + alup((size_t)NTOK*D_*2);
static constexpr size_t OFF_GATE = OFF_TOPI + alup((size_t)NTOK*4);
static constexpr size_t OFF_CNTR = OFF_GATE + alup((size_t)NTOK*8);
static constexpr size_t OFF_BTOK = OFF_CNTR + alup((size_t)1024);
static constexpr size_t OFF_BGT  = OFF_BTOK + alup((size_t)2*NBUCK*4);
static constexpr size_t OFF_OUT  = OFF_BGT  + alup((size_t)2*NBUCK*4);     // token outputs bf16 [token][d]; IS the head A-matrix
static constexpr size_t OFF_DEC  = OFF_OUT  + alup((size_t)NTOK*D_*2);
static constexpr size_t OFF_MEAND= OFF_DEC  + alup((size_t)NRW*96*4);
static constexpr size_t OFF_RSTDD= OFF_MEAND+ alup((size_t)NRW*8);
static constexpr size_t OFF_PED  = OFF_RSTDD+ alup((size_t)NRW*8);
static constexpr size_t OFF_WVG  = OFF_PED  + alup((size_t)P_*D_*8);
static constexpr size_t OFF_PEG  = OFF_WVG  + alup((size_t)16*8*8);
static constexpr size_t OFF_PG   = OFF_PEG  + alup((size_t)P_*E_*8);
static constexpr size_t OFF_PI   = OFF_PG   + alup((size_t)NRW*12*4);
// end ~= 195 MB

// ci ints at OFF_CNTR+128: [16..23]=cur1 [24..31]=cur2
// [32..40]=start1 [41..49]=start2 [50..58]=bstart1 [59..67]=bstart2

// ============ kernels ============

__global__ void k_xt(const float* __restrict__ x, float* __restrict__ xT){
  __shared__ float tile[32][33];
  int b = blockIdx.z;
  int v0 = blockIdx.x*32, l0 = blockIdx.y*32;
  int tx = threadIdx.x, ty = threadIdx.y;
  for(int i=ty;i<32;i+=8){
    int l = l0+i, v = v0+tx;
    tile[i][tx] = (v<NV_) ? x[((size_t)b*L_ + l)*NV_ + v] : 0.f;
  }
  __syncthreads();
  for(int i=ty;i<32;i+=8){
    int v = v0+i, l = l0+tx;
    if(v<NV_) xT[((size_t)(b*NV_+v))*L_ + l] = tile[tx][i];
  }
}

__global__ void k_stats(const float* __restrict__ xT, float* meanp, float* rstdp, float* stdp,
                        double* meand, double* rstdd){
  __shared__ double s1[256], s2[256];
  int r = blockIdx.x, t = threadIdx.x;
  double a = (double)xT[(size_t)r*L_ + t], b = (double)xT[(size_t)r*L_ + 256 + t];
  s1[t]=a+b; s2[t]=a*a+b*b;
  __syncthreads();
  for(int o=128;o>0;o>>=1){ if(t<o){ s1[t]+=s1[t+o]; s2[t]+=s2[t+o]; } __syncthreads(); }
  if(t==0){
    double m = s1[0]*(1.0/512.0);
    double var = s2[0]*(1.0/512.0) - m*m;
    double sd = sqrt(var + 1e-5);
    meanp[r]=(float)m; stdp[r]=(float)sd; rstdp[r]=(float)(1.0/sd);
    meand[r]=m; rstdd[r]=1.0/sd;
  }
}

__global__ void k_pe(float* pef, double* ped){
  int i = blockIdx.x*256 + threadIdx.x;   // 8192
  int p = i>>7, d = i&127;
  int k = d>>1;
  double div = exp(-(double)(2*k) * (9.210340371976184 /128.0)); // ln(10000)/128
  double ang = (double)p * div;
  double v = (d&1) ? cos(ang) : sin(ang);
  float vf = (float)v;
  pef[i] = vf;
  ped[i] = (double)vf;
}

__global__ void k_prep(const float* __restrict__ Wval, const float* __restrict__ Wg,
                       const double* __restrict__ ped, double* __restrict__ Wvg,
                       double* __restrict__ peg){
  int t = threadIdx.x;
  if(t<128){
    int j = t>>3, e = t&7;
    double acc = 0.0;
    for(int d=0;d<128;d++) acc += (double)Wval[j*128+d] * (double)Wg[d*8+e];
    Wvg[t] = acc;
  }
  for(int q=t;q<512;q+=256){
    int p = q>>3, e = q&7;
    double acc = 0.0;
    for(int d=0;d<128;d++) acc += ped[p*128+d] * (double)Wg[d*8+e];
    peg[q] = acc;
  }
}

__global__ void k_wt(const float* __restrict__ in, u16* __restrict__ outp, int R, int C){
  __shared__ float tile[32][33];
  int e = blockIdx.z;
  int c0 = blockIdx.x*32, r0 = blockIdx.y*32;
  const float* src = in + (size_t)e*R*C;
  u16* dst = outp + (size_t)e*R*C;
  int tx=threadIdx.x, ty=threadIdx.y;
  for(int i=ty;i<32;i+=8){
    int r=r0+i, c=c0+tx;
    tile[i][tx] = (r<R && c<C) ? src[(size_t)r*C+c] : 0.f;
  }
  __syncthreads();
  for(int i=ty;i<32;i+=8){
    int c=c0+i, r=r0+tx;
    if(c<C && r<R) dst[(size_t)c*R + r] = f2bf(tile[tx][i]);
  }
}

// permuted head-weight transpose: WhT2[o][p*128+d] = W_head[(d*64+p)*96 + o]
__global__ void k_wh(const float* __restrict__ Wh, u16* __restrict__ WhT2){
  __shared__ float tile[32][33];
  int d0 = blockIdx.x*32, o0 = blockIdx.y*32, p = blockIdx.z;
  int tx = threadIdx.x, ty = threadIdx.y;
  for(int i=ty;i<32;i+=8){
    int r = (d0+i)*64 + p;
    tile[i][tx] = Wh[(size_t)r*96 + o0 + tx];
  }
  __syncthreads();
  for(int i=ty;i<32;i+=8){
    int o = o0+i;
    WhT2[(size_t)o*DP_ + p*128 + d0 + tx] = f2bf(tile[tx][i]);
  }
}

__global__ __launch_bounds__(256) void k_embed(
    const float* __restrict__ xT, const float* __restrict__ meanp, const float* __restrict__ rstdp,
    const float* __restrict__ Wval, const float* __restrict__ pe,
    u16* __restrict__ tglob)
{
  __shared__ __align__(16) float xn[520];
  int r = blockIdx.x, t = threadIdx.x;
  float mean = meanp[r], rstd = rstdp[r];
  float v0 = (xT[(size_t)r*L_ + t]       - mean)*rstd;
  float v1 = (xT[(size_t)r*L_ + 256 + t] - mean)*rstd;
  xn[t] = v0; xn[t+256] = v1;
  if(t==255){
    #pragma unroll
    for(int i=512;i<520;i++) xn[i]=v1;   // edge pad
  }
  int d0 = (t & 63)*2;
  int p0 = t >> 6;
  float2 w[16];
  #pragma unroll
  for(int j=0;j<16;j++) w[j] = *(const float2*)(Wval + j*128 + d0);
  __syncthreads();

  for(int p=p0;p<64;p+=4){
    const float4* xp = (const float4*)(xn + p*8);
    float4 x0=xp[0], x1=xp[1], x2=xp[2], x3=xp[3];
    float xv[16];
    *(float4*)(xv+0)=x0; *(float4*)(xv+4)=x1; *(float4*)(xv+8)=x2; *(float4*)(xv+12)=x3;
    float2 pw = *(const float2*)(pe + p*128 + d0);
    float a0 = pw.x, a1 = pw.y;
    #pragma unroll
    for(int j=0;j<16;j++){ a0 += xv[j]*w[j].x; a1 += xv[j]*w[j].y; }
    u32 packed = (u32)f2bf(a0) | ((u32)f2bf(a1)<<16);
    *(u32*)(tglob + ((size_t)(r*64+p)*128 + d0)) = packed;
  }
}

__global__ __launch_bounds__(256) void k_gate(
    const float* __restrict__ xT, const double* __restrict__ meand, const double* __restrict__ rstdd,
    const double* __restrict__ Wvg, const double* __restrict__ peg,
    int* __restrict__ topip, float2* __restrict__ gatep,
    float* __restrict__ pg, int* __restrict__ pib)
{
  __shared__ double xn[520];
  __shared__ double lgt[64][9];
  int r = blockIdx.x, t = threadIdx.x;
  double m = meand[r], rs = rstdd[r];
  double v0 = ((double)xT[(size_t)r*L_ + t]       - m)*rs;
  double v1 = ((double)xT[(size_t)r*L_ + 256 + t] - m)*rs;
  xn[t]=v0; xn[t+256]=v1;
  if(t==255){
    #pragma unroll
    for(int i=512;i<520;i++) xn[i]=v1;
  }
  __syncthreads();
  for(int q=t;q<512;q+=256){
    int p = q>>3, e = q&7;
    double acc = peg[q];
    #pragma unroll
    for(int j=0;j<16;j++) acc += xn[p*8+j]*Wvg[j*8+e];
    lgt[p][e] = acc;
  }
  __syncthreads();
  if(t<64){
    int token = r*64 + t;
    double l0[8];
    #pragma unroll
    for(int e=0;e<8;e++) l0[e]=lgt[t][e];
    double mx=l0[0];
    #pragma unroll
    for(int e=1;e<8;e++) mx = fmax(mx,l0[e]);
    int i1=0; double b1v=l0[0];
    #pragma unroll
    for(int e=1;e<8;e++) if(l0[e]>b1v){b1v=l0[e]; i1=e;}
    int i2=-1; double b2v=-1e300;
    #pragma unroll
    for(int e=0;e<8;e++) if(e!=i1 && l0[e]>b2v){b2v=l0[e]; i2=e;}
    float pr[8]; float sum=0.f;
    #pragma unroll
    for(int e=0;e<8;e++){ pr[e]=__expf((float)(l0[e]-mx)); sum+=pr[e]; }
    float inv = 1.f/sum;
    #pragma unroll
    for(int e=0;e<8;e++) pr[e]*=inv;
    topip[token] = i1 | (i2<<8);
    gatep[token] = make_float2(pr[i1], pr[i2]);
    float lse = (float)mx + __logf(sum);
    #pragma unroll
    for(int e=0;e<8;e++){
      float v = pr[e];
      for(int o=32;o>0;o>>=1) v += __shfl_down(v,o);
      if(t==0) pg[r*12+e] = v;
    }
    {
      float z = lse*lse;
      for(int o=32;o>0;o>>=1) z += __shfl_down(z,o);
      if(t==0) pg[r*12+8] = z;
    }
    #pragma unroll
    for(int e=0;e<8;e++){
      u64 m1 = __ballot(i1==e);
      u64 m2 = __ballot(i2==e);
      if(t==0){
        pib[r*16+e]   = (int)__popcll(m1);
        pib[r*16+8+e] = (int)__popcll(m2);
      }
    }
  }
}

__global__ __launch_bounds__(256) void k_aux(const float* __restrict__ pg, const int* __restrict__ pib,
                                             int* __restrict__ ci, float* __restrict__ dout){
  __shared__ double sd[256];
  __shared__ int si[256];
  __shared__ double totd[9];
  __shared__ int toti[16];
  int t = threadIdx.x;
  double accd[9]; int acci[16];
  #pragma unroll
  for(int c=0;c<9;c++) accd[c]=0.0;
  #pragma unroll
  for(int c=0;c<16;c++) acci[c]=0;
  for(int r=t;r<NRW;r+=256){
    #pragma unroll
    for(int c=0;c<9;c++) accd[c] += (double)pg[r*12+c];
    #pragma unroll
    for(int c=0;c<16;c++) acci[c] += pib[r*16+c];
  }
  for(int c=0;c<9;c++){
    sd[t]=accd[c]; __syncthreads();
    for(int o=128;o>0;o>>=1){ if(t<o) sd[t]+=sd[t+o]; __syncthreads(); }
    if(t==0) totd[c]=sd[0];
    __syncthreads();
  }
  for(int c=0;c<16;c++){
    si[t]=acci[c]; __syncthreads();
    for(int o=128;o>0;o>>=1){ if(t<o) si[t]+=si[t+o]; __syncthreads(); }
    if(t==0) toti[c]=si[0];
    __syncthreads();
  }
  if(t==0){
    const double invN = 1.0/(double)NTOK;
    double bal = 0.0;
    int es1=0, bs1=0, es2=0, bs2=0;
    for(int e=0;e<8;e++){
      int c1 = toti[e], c2 = toti[8+e];
      bal += (totd[e]*invN) * ((double)(c1+c2) * invN * 0.5);
      ci[32+e]=es1; ci[16+e]=es1; ci[50+e]=bs1;
      ci[41+e]=es2; ci[24+e]=es2; ci[59+e]=bs2;
      es1 += c1; bs1 += (c1+127)>>7;
      es2 += c2; bs2 += (c2+127)>>7;
    }
    ci[40]=es1; ci[58]=bs1;
    ci[49]=es2; ci[67]=bs2;
    dout[493056] = (float)(0.01*8.0*bal + 0.001*(totd[8]*invN));
  }
}

__global__ __launch_bounds__(256) void k_scatter(const int* __restrict__ topip,
    const float2* __restrict__ gatep, int* __restrict__ ci,
    int* __restrict__ btok, float* __restrict__ bgt){
  __shared__ int lc[16]; __shared__ int lb[16];
  int t = threadIdx.x;
  int token = blockIdx.x*256 + t;
  if(t<16) lc[t]=0;
  __syncthreads();
  int ti = topip[token];
  float2 g = gatep[token];
  int e1 = ti & 255, e2 = (ti>>8)&255;
  int r1 = atomicAdd(&lc[e1],1);
  int r2 = atomicAdd(&lc[8+e2],1);
  __syncthreads();
  if(t<8)            lb[t] = atomicAdd(&ci[16+t],   lc[t]);
  else if(t<16)      lb[t] = atomicAdd(&ci[24+t-8], lc[t]);
  __syncthreads();
  int p1 = lb[e1]+r1, p2 = lb[8+e2]+r2;
  btok[p1] = token;         bgt[p1] = g.x;
  btok[NBUCK+p2] = token;   bgt[NBUCK+p2] = g.y;
}

// fused per-expert FFN v4: 32x32x16 MFMA, hc=64, padded Ws/Ss + XOR-16 As.
// LDS: As 32KB + Ws 18KB + Ss 18KB = 69.6KB -> 2 blocks/CU.
__global__ __launch_bounds__(256,2) void k_expert(
    const u16* __restrict__ tglob,
    const u16* __restrict__ W1T, const u16* __restrict__ W2T,
    const float* __restrict__ b1g, const float* __restrict__ b2g,
    const int* __restrict__ ci,
    const int* __restrict__ btok, const float* __restrict__ bgt,
    u16* __restrict__ outg, int slot)
{
  __shared__ __align__(16) u16 As[128*128];   // XOR-16 swizzled
  __shared__ __align__(16) u16 Ws[9216];      // W1c [64][136] / W2c [128][72]
  __shared__ __align__(16) u16 Ss[128*72];    // hidden, padded stride 72

  int bid = blockIdx.x, t = threadIdx.x;
  int stB = 32 + slot*9, bsB = 50 + slot*9;
  int boff = slot*NBUCK;
  if(bid >= ci[bsB+8]) return;
  int e = 0;
  #pragma unroll
  for(int k2=1;k2<8;k2++) if(bid >= ci[bsB+k2]) e = k2;
  int row0 = ci[stB+e] + (bid - ci[bsB+e])*128;
  int rend = ci[stB+e+1];

  if(t<128){
    int pos = row0+t;
    ((int*)Ss)[t] = (pos<rend) ? btok[boff+pos] : -1;
  }
  __syncthreads();
  { // gather A rows, XOR-16 swizzled groups of 8 u16
    int lr = t>>1, half = t&1;
    int token = ((int*)Ss)[lr];
    int tk = (token>=0) ? token : 0;
    const u16* src = tglob + (size_t)tk*128 + half*64;
    #pragma unroll
    for(int i=0;i<8;i++){
      int g = half*8 + i;
      uint4 v = *(const uint4*)(src + i*8);
      *(uint4*)(As + lr*128 + ((g ^ (lr&15))<<3)) = v;
    }
  }
  // first in-loop sync covers gather->GEMM1 and Ss-token-read->Ss-overwrite.

  int wid = t>>6, lane = t&63;
  int m = lane&31, hi = lane>>5;
  int rb = wid*32;                 // wave owns token rows rb..rb+31
  int rowA = rb + m;
  int cA = m & 15;                 // XOR key for A (rb multiple of 32)

  f32x16 accO[4];
  const f32x16 z16 = {0,0,0,0,0,0,0,0,0,0,0,0,0,0,0,0};
  #pragma unroll
  for(int nt=0;nt<4;nt++) accO[nt] = z16;

  for(int hc=0;hc<8;hc++){
    { // stage W1c [64h][128d] -> Ws stride 136
      int hr = t>>2, q = t&3;
      const u16* src = W1T + ((size_t)e*H_ + hc*64 + hr)*128 + q*32;
      u16* dst = Ws + hr*136 + q*32;
      *(uint4*)(dst)    = *(const uint4*)(src);
      *(uint4*)(dst+8)  = *(const uint4*)(src+8);
      *(uint4*)(dst+16) = *(const uint4*)(src+16);
      *(uint4*)(dst+24) = *(const uint4*)(src+24);
    }
    __syncthreads();                       // S1: W1c ready (and As on first iter)
    // GEMM1: S(128x64) = A(128x128)@W1c, two 32-wide h tiles
    f32x16 acc1[2];
    acc1[0] = z16; acc1[1] = z16;
    #pragma unroll
    for(int ks=0;ks<8;ks++){
      int gA = 2*ks + hi;
      bf16x8 a  = *(const bf16x8*)(As + rowA*128 + ((gA ^ cA)<<3));
      bf16x8 b0 = *(const bf16x8*)(Ws + m*136        + ks*16 + hi*8);
      bf16x8 b1 = *(const bf16x8*)(Ws + (32+m)*136   + ks*16 + hi*8);
      acc1[0] = MFMA32(a, b0, acc1[0]);
      acc1[1] = MFMA32(a, b1, acc1[1]);
    }
    float bv0 = b1g[e*H_ + hc*64 + m];
    float bv1 = b1g[e*H_ + hc*64 + 32 + m];
    #pragma unroll
    for(int reg=0; reg<16; reg++){
      int rl = (reg&3) + 8*(reg>>2) + 4*hi;
      int row = rb + rl;
      Ss[row*72 + m]      = f2bf(gelu_f(acc1[0][reg] + bv0));
      Ss[row*72 + 32 + m] = f2bf(gelu_f(acc1[1][reg] + bv1));
    }
    __syncthreads();                       // S2: Ss ready, W1c consumed
    { // stage W2c [128d][64h] -> Ws stride 72
      int dr = t>>1, q = t&1;
      const u16* src = W2T + ((size_t)e*D_ + dr)*H_ + hc*64 + q*32;
      u16* dst = Ws + dr*72 + q*32;
      *(uint4*)(dst)    = *(const uint4*)(src);
      *(uint4*)(dst+8)  = *(const uint4*)(src+8);
      *(uint4*)(dst+16) = *(const uint4*)(src+16);
      *(uint4*)(dst+24) = *(const uint4*)(src+24);
    }
    __syncthreads();                       // S3: W2c ready
    // GEMM2: accO += S(128x64)@W2c, four 32-wide d tiles
    #pragma unroll
    for(int ks=0;ks<4;ks++){
      bf16x8 a = *(const bf16x8*)(Ss + rowA*72 + ks*16 + hi*8);
      #pragma unroll
      for(int nt=0;nt<4;nt++){
        bf16x8 b = *(const bf16x8*)(Ws + (nt*32+m)*72 + ks*16 + hi*8);
        accO[nt] = MFMA32(a, b, accO[nt]);
      }
    }
    __syncthreads();                       // S4: Ss/W2c consumed
  }

  // epilogue: reload token/gate, scale, transpose via As, coalesced (RMW) store
  if(t<128){
    int pos = row0+t;
    bool v = pos<rend;
    ((float*)Ss)[t]   = v ? bgt[boff+pos]  : 0.f;
    ((int*)Ss)[128+t] = v ? btok[boff+pos] : -1;
  }
  __syncthreads();
  float b2v[4];
  #pragma unroll
  for(int nt=0;nt<4;nt++) b2v[nt] = b2g[e*128 + nt*32 + m];
  #pragma unroll
  for(int reg=0; reg<16; reg++){
    int rl = (reg&3) + 8*(reg>>2) + 4*hi;
    int row = rb + rl;
    float gt = ((float*)Ss)[row];
    int key = row & 15;
    #pragma unroll
    for(int nt=0;nt<4;nt++){
      int d = nt*32 + m;
      float v = (accO[nt][reg] + b2v[nt]) * gt;
      As[row*128 + (((d>>3) ^ key)<<3) + (d&7)] = f2bf(v);
    }
  }
  __syncthreads();
  {
    int lr = t>>1, half = t&1;
    int token = ((int*)Ss)[128+lr];
    if(token>=0){
      u16* dst = outg + (size_t)token*128 + half*64;
      #pragma unroll
      for(int i=0;i<8;i++){
        int g = half*8 + i;
        uint4 v = *(const uint4*)(As + lr*128 + ((g ^ (lr&15))<<3));
        if(slot==1){
          uint4 o = *(const uint4*)(dst + i*8);
          v.x = bfadd2(v.x, o.x); v.y = bfadd2(v.y, o.y);
          v.z = bfadd2(v.z, o.z); v.w = bfadd2(v.w, o.w);
        }
        *(uint4*)(dst + i*8) = v;
      }
    }
  }
}

// head GEMM: A = outg (k' = p*128+d natural order), B = WhT2[o][k'].
// wave owns 16 rows, 8-way K-split, no LDS, plain stores to dec8.
__global__ __launch_bounds__(256) void k_head(const u16* __restrict__ Aout,
    const u16* __restrict__ WhT2, float* __restrict__ dec8){
  int bid = blockIdx.x;                 // 81 mtiles x 8 ksegs
  int mb = bid>>3, kseg = bid&7;
  int t = threadIdx.x, wid = t>>6, lane = t&63;
  int quad = lane>>4, li = lane&15;
  int r0 = mb*64 + wid*16;
  int rowA = r0 + li; if(rowA >= NRW) rowA = NRW-1;
  const u16* aptr = Aout + (size_t)rowA*DP_ + kseg*1024 + quad*8;
  const u16* bptr = WhT2 + (size_t)li*DP_  + kseg*1024 + quad*8;
  f32x4 acc[6];
  #pragma unroll
  for(int j=0;j<6;j++) acc[j]=(f32x4){0,0,0,0};
  #pragma unroll 4
  for(int ks=0;ks<32;ks++){
    bf16x8 af = *(const bf16x8*)(aptr + ks*32);
    #pragma unroll
    for(int nt=0;nt<6;nt++){
      bf16x8 bw = *(const bf16x8*)(bptr + (size_t)nt*16*DP_ + ks*32);
      acc[nt] = MFMA16(af, bw, acc[nt]);
    }
  }
  float* dst = dec8 + (size_t)kseg*NRW*96;
  #pragma unroll
  for(int nt=0;nt<6;nt++)
    #pragma unroll
    for(int rg=0;rg<4;rg++){
      int mm = r0 + quad*4 + rg;
      if(mm < NRW) dst[(size_t)mm*96 + nt*16 + li] = acc[nt][rg];
    }
}

// sum 8 k-segments + transpose + bias + denorm
__global__ void k_final(const float* __restrict__ dec8, const float* __restrict__ bhead,
    const float* __restrict__ stdp, const float* __restrict__ meanp, float* __restrict__ outp){
  __shared__ float s[64*97];
  int b = blockIdx.y, v0 = blockIdx.x*64;
  int t = threadIdx.x;
  for(int i=t;i<6144;i+=256){
    int vi = i/96, o = i - vi*96;
    int v = v0+vi;
    float acc = 0.f;
    if(v<NV_){
      size_t base = (size_t)(b*NV_+v)*96 + o;
      #pragma unroll
      for(int ks=0;ks<8;ks++) acc += dec8[(size_t)ks*NRW*96 + base];
    }
    s[vi*97+o] = acc;
  }
  __syncthreads();
  for(int i=t;i<6144;i+=256){
    int o = i>>6, vi = i&63;
    int v = v0+vi;
    if(v<NV_){
      int r = b*NV_+v;
      outp[((size_t)b*96 + o)*NV_ + v] = (s[vi*97+o] + bhead[o])*stdp[r] + meanp[r];
    }
  }
}

// ============ launcher ============
extern "C" void kernel_launch(void* const* d_in, const int* in_sizes, int n_in,
                              void* d_out, int out_size, void* d_ws, size_t ws_size,
                              hipStream_t stream){
  const float* x_enc = (const float*)d_in[0];
  const float* W_val = (const float*)d_in[4];
  const float* W_g   = (const float*)d_in[5];
  const float* W1    = (const float*)d_in[6];
  const float* b1    = (const float*)d_in[7];
  const float* W2    = (const float*)d_in[8];
  const float* b2    = (const float*)d_in[9];
  const float* W_head= (const float*)d_in[10];
  const float* b_head= (const float*)d_in[11];
  float* outp = (float*)d_out;
  char* ws = (char*)d_ws;

  float* meanp = (float*)(ws+OFF_MEAN);
  float* rstdp = (float*)(ws+OFF_RSTD);
  float* stdp  = (float*)(ws+OFF_STD);
  float* xT    = (float*)(ws+OFF_XT);
  float* pe    = (float*)(ws+OFF_PE);
  u16*   W1T   = (u16*)(ws+OFF_W1T);
  u16*   W2T   = (u16*)(ws+OFF_W2T);
  u16*   WhT2  = (u16*)(ws+OFF_WHT);
  u16*   tglob = (u16*)(ws+OFF_T);
  float* dec8  = (float*)(ws+OFF_T);    // aliases tglob (dead after expert passes)
  int*   topip = (int*)(ws+OFF_TOPI);
  float2* gatep= (float2*)(ws+OFF_GATE);
  int*   ci    = (int*)(ws+OFF_CNTR+128);
  int*   btok  = (int*)(ws+OFF_BTOK);
  float* bgt   = (float*)(ws+OFF_BGT);
  u16*   outg  = (u16*)(ws+OFF_OUT);
  double* meand= (double*)(ws+OFF_MEAND);
  double* rstdd= (double*)(ws+OFF_RSTDD);
  double* ped  = (double*)(ws+OFF_PED);
  double* Wvg  = (double*)(ws+OFF_WVG);
  double* peg  = (double*)(ws+OFF_PEG);
  float* pg    = (float*)(ws+OFF_PG);
  int*   pib   = (int*)(ws+OFF_PI);

  hipMemsetAsync(ws+OFF_CNTR, 0, 1024, stream);

  k_xt<<<dim3(11,16,B_), dim3(32,8), 0, stream>>>(x_enc, xT);
  k_stats<<<NRW, 256, 0, stream>>>(xT, meanp, rstdp, stdp, meand, rstdd);
  k_pe<<<32, 256, 0, stream>>>(pe, ped);
  k_prep<<<1, 256, 0, stream>>>(W_val, W_g, ped, Wvg, peg);
  k_wt<<<dim3(16,4,E_), dim3(32,8), 0, stream>>>(W1, W1T, 128, 512);
  k_wt<<<dim3(4,16,E_), dim3(32,8), 0, stream>>>(W2, W2T, 512, 128);
  k_wh<<<dim3(4,3,64), dim3(32,8), 0, stream>>>(W_head, WhT2);
  k_embed<<<NRW, 256, 0, stream>>>(xT, meanp, rstdp, W_val, pe, tglob);
  k_gate<<<NRW, 256, 0, stream>>>(xT, meand, rstdd, Wvg, peg, topip, gatep, pg, pib);
  k_aux<<<1, 256, 0, stream>>>(pg, pib, ci, outp);
  k_scatter<<<NTOK/256, 256, 0, stream>>>(topip, gatep, ci, btok, bgt);
  k_expert<<<2576, 256, 0, stream>>>(tglob, W1T, W2T, b1, b2, ci, btok, bgt, outg, 0);
  k_expert<<<2576, 256, 0, stream>>>(tglob, W1T, W2T, b1, b2, ci, btok, bgt, outg, 1);
  k_head<<<648, 256, 0, stream>>>(outg, WhT2, dec8);
  k_final<<<dim3(6,B_), 256, 0, stream>>>(dec8, b_head, stdp, meanp, outp);
}

// Round 8
// 737.333 us; speedup vs baseline: 2.7010x; 1.0156x over previous
//
#include <hip/hip_runtime.h>
#include <hip/hip_bf16.h>

typedef unsigned short u16;
typedef unsigned int   u32;
typedef unsigned long long u64;
typedef __attribute__((ext_vector_type(8))) short bf16x8;
typedef __attribute__((ext_vector_type(4))) float f32x4;
typedef __attribute__((ext_vector_type(16))) float f32x16;

#define MFMA16(a,b,c) __builtin_amdgcn_mfma_f32_16x16x32_bf16(a,b,c,0,0,0)
#define MFMA32(a,b,c) __builtin_amdgcn_mfma_f32_32x32x16_bf16(a,b,c,0,0,0)

// ---- problem dims ----
#define NV_   321
#define B_    16
#define L_    512
#define D_    128
#define P_    64
#define E_    8
#define H_    512
#define NRW   5136        // B*NV
#define NTOK  328704      // NRW*P
#define DP_   8192        // D*P
#define NBUCK 329728      // NTOK + 8*128 padding

static __device__ __forceinline__ u16 f2bf(float f){
  __hip_bfloat16 h = __float2bfloat16(f);
  return *reinterpret_cast<u16*>(&h);
}

// sigma-form tanh-GELU: x*sigma(1.5958x(1+0.044715x^2)); exp2 maps to v_exp_f32
static __device__ __forceinline__ float gelu_f(float x){
  float x2 = x*x;
  float p  = __builtin_fmaf(-0.1029433f, x2, -2.3022083f);
  float a  = x*p;
  float en = exp2f(a);
  float r  = __builtin_amdgcn_rcpf(1.0f + en);
  return x*r;
}

static __device__ __forceinline__ u32 bfadd2(u32 a, u32 b){
  float lo = __uint_as_float(a<<16)           + __uint_as_float(b<<16);
  float hi = __uint_as_float(a&0xffff0000u)   + __uint_as_float(b&0xffff0000u);
  return (u32)f2bf(lo) | ((u32)f2bf(hi)<<16);
}

// ============ workspace layout (bytes) — end ~193 MB (budget 256 MiB) ============
static constexpr size_t alup(size_t x){ return (x + 255) & ~(size_t)255; }
static constexpr size_t OFF_MEAN = 0;
static constexpr size_t OFF_RSTD = OFF_MEAN + alup((size_t)NRW*4);
static constexpr size_t OFF_STD  = OFF_RSTD + alup((size_t)NRW*4);
static constexpr size_t OFF_XT   = OFF_STD  + alup((size_t)NRW*4);
static constexpr size_t OFF_PE   = OFF_XT   + alup((size_t)NRW*L_*4);
static constexpr size_t OFF_W1T  = OFF_PE   + alup((size_t)P_*D_*4);
static constexpr size_t OFF_W2T  = OFF_W1T  + alup((size_t)E_*H_*D_*2);
static constexpr size_t OFF_WHT  = OFF_W2T  + alup((size_t)E_*D_*H_*2);
static constexpr size_t OFF_T    = OFF_WHT  + alup((size_t)96*DP_*2);      // tokens bf16; later ALIASED as dec8
static constexpr size_t OFF_TOPI = OFF_T    + alup((size_t)NTOK*D_*2);
static constexpr size_t OFF_GATE = OFF_TOPI + alup((size_t)NTOK*4);
static constexpr size_t OFF_CNTR = OFF_GATE + alup((size_t)NTOK*8);
static constexpr size_t OFF_BTOK = OFF_CNTR + alup((size_t)1024);
static constexpr size_t OFF_BGT  = OFF_BTOK + alup((size_t)2*NBUCK*4);
static constexpr size_t OFF_OUT  = OFF_BGT  + alup((size_t)2*NBUCK*4);     // combined token outputs bf16 [token][d]
static constexpr size_t OFF_MEAND= OFF_OUT  + alup((size_t)NTOK*D_*2);
static constexpr size_t OFF_RSTDD= OFF_MEAND+ alup((size_t)NRW*8);
static constexpr size_t OFF_WVG  = OFF_RSTDD+ alup((size_t)NRW*8);
static constexpr size_t OFF_PEG  = OFF_WVG  + alup((size_t)16*8*8);
static constexpr size_t OFF_PG   = OFF_PEG  + alup((size_t)P_*E_*8);
static constexpr size_t OFF_PI   = OFF_PG   + alup((size_t)NRW*12*4);

// ci ints at OFF_CNTR+128: [16..23]=cur1 [24..31]=cur2
// [32..40]=start1 [41..49]=start2 [50..58]=bstart1 [59..67]=bstart2

// ============ kernels ============

__global__ void k_xt(const float* __restrict__ x, float* __restrict__ xT){
  __shared__ float tile[32][33];
  int b = blockIdx.z;
  int v0 = blockIdx.x*32, l0 = blockIdx.y*32;
  int tx = threadIdx.x, ty = threadIdx.y;
  for(int i=ty;i<32;i+=8){
    int l = l0+i, v = v0+tx;
    tile[i][tx] = (v<NV_) ? x[((size_t)b*L_ + l)*NV_ + v] : 0.f;
  }
  __syncthreads();
  for(int i=ty;i<32;i+=8){
    int v = v0+i, l = l0+tx;
    if(v<NV_) xT[((size_t)(b*NV_+v))*L_ + l] = tile[tx][i];
  }
}

__global__ void k_stats(const float* __restrict__ xT, float* meanp, float* rstdp, float* stdp,
                        double* meand, double* rstdd){
  __shared__ double s1[256], s2[256];
  int r = blockIdx.x, t = threadIdx.x;
  double a = (double)xT[(size_t)r*L_ + t], b = (double)xT[(size_t)r*L_ + 256 + t];
  s1[t]=a+b; s2[t]=a*a+b*b;
  __syncthreads();
  for(int o=128;o>0;o>>=1){ if(t<o){ s1[t]+=s1[t+o]; s2[t]+=s2[t+o]; } __syncthreads(); }
  if(t==0){
    double m = s1[0]*(1.0/512.0);
    double var = s2[0]*(1.0/512.0) - m*m;
    double sd = sqrt(var + 1e-5);
    meanp[r]=(float)m; stdp[r]=(float)sd; rstdp[r]=(float)(1.0/sd);
    meand[r]=m; rstdd[r]=1.0/sd;
  }
}

// PE (float32 np semantics) + Wvg=W_val@W_g, peg=pe@W_g in fp64, one block
__global__ void k_prep(const float* __restrict__ Wval, const float* __restrict__ Wg,
                       float* __restrict__ pef, double* __restrict__ Wvg,
                       double* __restrict__ peg){
  int t = threadIdx.x;
  for(int i=t;i<8192;i+=256){
    int p = i>>7, d = i&127, k = d>>1;
    double div = exp(-(double)(2*k) * (9.210340371976184 /128.0)); // ln(10000)/128
    double ang = (double)p * div;
    double v = (d&1) ? cos(ang) : sin(ang);
    pef[i] = (float)v;
  }
  __syncthreads();
  if(t<128){
    int j = t>>3, e = t&7;
    double acc = 0.0;
    for(int d=0;d<128;d++) acc += (double)Wval[j*128+d] * (double)Wg[d*8+e];
    Wvg[t] = acc;
  }
  for(int q=t;q<512;q+=256){
    int p = q>>3, e = q&7;
    double acc = 0.0;
    for(int d=0;d<128;d++) acc += (double)pef[p*128+d] * (double)Wg[d*8+e];
    peg[q] = acc;
  }
}

__global__ void k_wt(const float* __restrict__ in, u16* __restrict__ outp, int R, int C){
  __shared__ float tile[32][33];
  int e = blockIdx.z;
  int c0 = blockIdx.x*32, r0 = blockIdx.y*32;
  const float* src = in + (size_t)e*R*C;
  u16* dst = outp + (size_t)e*R*C;
  int tx=threadIdx.x, ty=threadIdx.y;
  for(int i=ty;i<32;i+=8){
    int r=r0+i, c=c0+tx;
    tile[i][tx] = (r<R && c<C) ? src[(size_t)r*C+c] : 0.f;
  }
  __syncthreads();
  for(int i=ty;i<32;i+=8){
    int c=c0+i, r=r0+tx;
    if(c<C && r<R) dst[(size_t)c*R + r] = f2bf(tile[tx][i]);
  }
}

// permuted head-weight transpose: WhT2[o][p*128+d] = W_head[(d*64+p)*96 + o]
__global__ void k_wh(const float* __restrict__ Wh, u16* __restrict__ WhT2){
  __shared__ float tile[32][33];
  int d0 = blockIdx.x*32, o0 = blockIdx.y*32, p = blockIdx.z;
  int tx = threadIdx.x, ty = threadIdx.y;
  for(int i=ty;i<32;i+=8){
    int r = (d0+i)*64 + p;
    tile[i][tx] = Wh[(size_t)r*96 + o0 + tx];
  }
  __syncthreads();
  for(int i=ty;i<32;i+=8){
    int o = o0+i;
    WhT2[(size_t)o*DP_ + p*128 + d0 + tx] = f2bf(tile[tx][i]);
  }
}

__global__ __launch_bounds__(256) void k_embed(
    const float* __restrict__ xT, const float* __restrict__ meanp, const float* __restrict__ rstdp,
    const float* __restrict__ Wval, const float* __restrict__ pe,
    u16* __restrict__ tglob)
{
  __shared__ __align__(16) float xn[520];
  int r = blockIdx.x, t = threadIdx.x;
  float mean = meanp[r], rstd = rstdp[r];
  float v0 = (xT[(size_t)r*L_ + t]       - mean)*rstd;
  float v1 = (xT[(size_t)r*L_ + 256 + t] - mean)*rstd;
  xn[t] = v0; xn[t+256] = v1;
  if(t==255){
    #pragma unroll
    for(int i=512;i<520;i++) xn[i]=v1;   // edge pad
  }
  int d0 = (t & 63)*2;
  int p0 = t >> 6;
  float2 w[16];
  #pragma unroll
  for(int j=0;j<16;j++) w[j] = *(const float2*)(Wval + j*128 + d0);
  __syncthreads();

  for(int p=p0;p<64;p+=4){
    const float4* xp = (const float4*)(xn + p*8);
    float4 x0=xp[0], x1=xp[1], x2=xp[2], x3=xp[3];
    float xv[16];
    *(float4*)(xv+0)=x0; *(float4*)(xv+4)=x1; *(float4*)(xv+8)=x2; *(float4*)(xv+12)=x3;
    float2 pw = *(const float2*)(pe + p*128 + d0);
    float a0 = pw.x, a1 = pw.y;
    #pragma unroll
    for(int j=0;j<16;j++){ a0 += xv[j]*w[j].x; a1 += xv[j]*w[j].y; }
    u32 packed = (u32)f2bf(a0) | ((u32)f2bf(a1)<<16);
    *(u32*)(tglob + ((size_t)(r*64+p)*128 + d0)) = packed;
  }
}

__global__ __launch_bounds__(256) void k_gate(
    const float* __restrict__ xT, const double* __restrict__ meand, const double* __restrict__ rstdd,
    const double* __restrict__ Wvg, const double* __restrict__ peg,
    int* __restrict__ topip, float2* __restrict__ gatep,
    float* __restrict__ pg, int* __restrict__ pib)
{
  __shared__ double xn[520];
  __shared__ double lgt[64][9];
  int r = blockIdx.x, t = threadIdx.x;
  double m = meand[r], rs = rstdd[r];
  double v0 = ((double)xT[(size_t)r*L_ + t]       - m)*rs;
  double v1 = ((double)xT[(size_t)r*L_ + 256 + t] - m)*rs;
  xn[t]=v0; xn[t+256]=v1;
  if(t==255){
    #pragma unroll
    for(int i=512;i<520;i++) xn[i]=v1;
  }
  __syncthreads();
  for(int q=t;q<512;q+=256){
    int p = q>>3, e = q&7;
    double acc = peg[q];
    #pragma unroll
    for(int j=0;j<16;j++) acc += xn[p*8+j]*Wvg[j*8+e];
    lgt[p][e] = acc;
  }
  __syncthreads();
  if(t<64){
    int token = r*64 + t;
    double l0[8];
    #pragma unroll
    for(int e=0;e<8;e++) l0[e]=lgt[t][e];
    double mx=l0[0];
    #pragma unroll
    for(int e=1;e<8;e++) mx = fmax(mx,l0[e]);
    int i1=0; double b1v=l0[0];
    #pragma unroll
    for(int e=1;e<8;e++) if(l0[e]>b1v){b1v=l0[e]; i1=e;}
    int i2=-1; double b2v=-1e300;
    #pragma unroll
    for(int e=0;e<8;e++) if(e!=i1 && l0[e]>b2v){b2v=l0[e]; i2=e;}
    float pr[8]; float sum=0.f;
    #pragma unroll
    for(int e=0;e<8;e++){ pr[e]=__expf((float)(l0[e]-mx)); sum+=pr[e]; }
    float inv = 1.f/sum;
    #pragma unroll
    for(int e=0;e<8;e++) pr[e]*=inv;
    topip[token] = i1 | (i2<<8);
    gatep[token] = make_float2(pr[i1], pr[i2]);
    float lse = (float)mx + __logf(sum);
    #pragma unroll
    for(int e=0;e<8;e++){
      float v = pr[e];
      for(int o=32;o>0;o>>=1) v += __shfl_down(v,o);
      if(t==0) pg[r*12+e] = v;
    }
    {
      float z = lse*lse;
      for(int o=32;o>0;o>>=1) z += __shfl_down(z,o);
      if(t==0) pg[r*12+8] = z;
    }
    #pragma unroll
    for(int e=0;e<8;e++){
      u64 m1 = __ballot(i1==e);
      u64 m2 = __ballot(i2==e);
      if(t==0){
        pib[r*16+e]   = (int)__popcll(m1);
        pib[r*16+8+e] = (int)__popcll(m2);
      }
    }
  }
}

__global__ __launch_bounds__(256) void k_aux(const float* __restrict__ pg, const int* __restrict__ pib,
                                             int* __restrict__ ci, float* __restrict__ dout){
  __shared__ double sd[256];
  __shared__ int si[256];
  __shared__ double totd[9];
  __shared__ int toti[16];
  int t = threadIdx.x;
  double accd[9]; int acci[16];
  #pragma unroll
  for(int c=0;c<9;c++) accd[c]=0.0;
  #pragma unroll
  for(int c=0;c<16;c++) acci[c]=0;
  for(int r=t;r<NRW;r+=256){
    #pragma unroll
    for(int c=0;c<9;c++) accd[c] += (double)pg[r*12+c];
    #pragma unroll
    for(int c=0;c<16;c++) acci[c] += pib[r*16+c];
  }
  for(int c=0;c<9;c++){
    sd[t]=accd[c]; __syncthreads();
    for(int o=128;o>0;o>>=1){ if(t<o) sd[t]+=sd[t+o]; __syncthreads(); }
    if(t==0) totd[c]=sd[0];
    __syncthreads();
  }
  for(int c=0;c<16;c++){
    si[t]=acci[c]; __syncthreads();
    for(int o=128;o>0;o>>=1){ if(t<o) si[t]+=si[t+o]; __syncthreads(); }
    if(t==0) toti[c]=si[0];
    __syncthreads();
  }
  if(t==0){
    const double invN = 1.0/(double)NTOK;
    double bal = 0.0;
    int es1=0, bs1=0, es2=0, bs2=0;
    for(int e=0;e<8;e++){
      int c1 = toti[e], c2 = toti[8+e];
      bal += (totd[e]*invN) * ((double)(c1+c2) * invN * 0.5);
      ci[32+e]=es1; ci[16+e]=es1; ci[50+e]=bs1;
      ci[41+e]=es2; ci[24+e]=es2; ci[59+e]=bs2;
      es1 += c1; bs1 += (c1+127)>>7;
      es2 += c2; bs2 += (c2+127)>>7;
    }
    ci[40]=es1; ci[58]=bs1;
    ci[49]=es2; ci[67]=bs2;
    dout[493056] = (float)(0.01*8.0*bal + 0.001*(totd[8]*invN));
  }
}

__global__ __launch_bounds__(256) void k_scatter(const int* __restrict__ topip,
    const float2* __restrict__ gatep, int* __restrict__ ci,
    int* __restrict__ btok, float* __restrict__ bgt){
  __shared__ int lc[16]; __shared__ int lb[16];
  int t = threadIdx.x;
  int token = blockIdx.x*256 + t;
  if(t<16) lc[t]=0;
  __syncthreads();
  int ti = topip[token];
  float2 g = gatep[token];
  int e1 = ti & 255, e2 = (ti>>8)&255;
  int r1 = atomicAdd(&lc[e1],1);
  int r2 = atomicAdd(&lc[8+e2],1);
  __syncthreads();
  if(t<8)            lb[t] = atomicAdd(&ci[16+t],   lc[t]);
  else if(t<16)      lb[t] = atomicAdd(&ci[24+t-8], lc[t]);
  __syncthreads();
  int p1 = lb[e1]+r1, p2 = lb[8+e2]+r2;
  btok[p1] = token;         bgt[p1] = g.x;
  btok[NBUCK+p2] = token;   bgt[NBUCK+p2] = g.y;
}

// fused per-expert FFN v5: MFMA32, hc=32, 52KB LDS -> 3 blocks/CU.
// pass 0: OUT = g1*(h+b2); pass 1: OUT += g2*(h+b2) (race-free per pass).
__global__ __launch_bounds__(256,3) void k_expert(
    const u16* __restrict__ tglob,
    const u16* __restrict__ W1T, const u16* __restrict__ W2T,
    const float* __restrict__ b1g, const float* __restrict__ b2g,
    const int* __restrict__ ci,
    const int* __restrict__ btok, const float* __restrict__ bgt,
    u16* __restrict__ outg, int slot)
{
  __shared__ __align__(16) u16 As[128*128];   // 32 KB, XOR-16 swizzled
  __shared__ __align__(16) u16 Ws[5120];      // W1c [32][136]=8.5KB / W2c [128][40]=10KB
  __shared__ __align__(16) u16 Ss[128*40];    // 10 KB, hidden (padded stride 40)

  int bid = blockIdx.x, t = threadIdx.x;
  int stB = 32 + slot*9, bsB = 50 + slot*9;
  int boff = slot*NBUCK;
  if(bid >= ci[bsB+8]) return;
  int e = 0;
  #pragma unroll
  for(int k2=1;k2<8;k2++) if(bid >= ci[bsB+k2]) e = k2;
  int row0 = ci[stB+e] + (bid - ci[bsB+e])*128;
  int rend = ci[stB+e+1];

  if(t<128){
    int pos = row0+t;
    ((int*)Ss)[t] = (pos<rend) ? btok[boff+pos] : -1;
  }
  __syncthreads();
  { // gather A rows, XOR-16 swizzled groups of 8 u16
    int lr = t>>1, half = t&1;
    int token = ((int*)Ss)[lr];
    int tk = (token>=0) ? token : 0;
    const u16* src = tglob + (size_t)tk*128 + half*64;
    #pragma unroll
    for(int i=0;i<8;i++){
      int g = half*8 + i;
      uint4 v = *(const uint4*)(src + i*8);
      *(uint4*)(As + lr*128 + ((g ^ (lr&15))<<3)) = v;
    }
  }
  // first in-loop sync covers gather->GEMM1 and Ss-token-read->Ss-overwrite.

  int wid = t>>6, lane = t&63;
  int m = lane&31, hi = lane>>5;
  int rb = wid*32;                 // wave owns token rows rb..rb+31
  int rowA = rb + m;
  int cA = m & 15;                 // XOR key (rb multiple of 32)

  f32x16 accO[4];
  const f32x16 z16 = {0,0,0,0,0,0,0,0,0,0,0,0,0,0,0,0};
  #pragma unroll
  for(int nt=0;nt<4;nt++) accO[nt] = z16;

  for(int hc=0;hc<16;hc++){
    { // stage W1c [32h][128d] -> Ws stride 136
      int hr = t>>3, q = t&7;
      const u16* src = W1T + ((size_t)e*H_ + hc*32 + hr)*128 + q*16;
      u16* dst = Ws + hr*136 + q*16;
      *(uint4*)(dst)   = *(const uint4*)(src);
      *(uint4*)(dst+8) = *(const uint4*)(src+8);
    }
    __syncthreads();                       // S1: W1c ready (As on first iter)
    // GEMM1: S(128x32) = A(128x128)@W1c
    f32x16 acc1 = z16;
    #pragma unroll
    for(int ks=0;ks<8;ks++){
      int g = ks*2 + hi;
      bf16x8 a = *(const bf16x8*)(As + rowA*128 + ((g ^ cA)<<3));
      bf16x8 b = *(const bf16x8*)(Ws + m*136 + ks*16 + hi*8);
      acc1 = MFMA32(a, b, acc1);
    }
    float bv = b1g[e*H_ + hc*32 + m];
    #pragma unroll
    for(int reg=0; reg<16; reg++){
      int rl = (reg&3) + 8*(reg>>2) + 4*hi;
      int row = rb + rl;
      Ss[row*40 + m] = f2bf(gelu_f(acc1[reg] + bv));
    }
    __syncthreads();                       // S2: Ss ready, W1c consumed
    { // stage W2c [128d][32h] -> Ws stride 40
      int dr = t>>1, q = t&1;
      const u16* src = W2T + ((size_t)e*D_ + dr)*H_ + hc*32 + q*16;
      u16* dst = Ws + dr*40 + q*16;
      *(uint4*)(dst)   = *(const uint4*)(src);
      *(uint4*)(dst+8) = *(const uint4*)(src+8);
    }
    __syncthreads();                       // S3: W2c ready
    // GEMM2: accO += S(128x32)@W2c, four 32-wide d tiles
    #pragma unroll
    for(int ks=0;ks<2;ks++){
      bf16x8 a = *(const bf16x8*)(Ss + rowA*40 + ks*16 + hi*8);
      #pragma unroll
      for(int nt=0;nt<4;nt++){
        bf16x8 b = *(const bf16x8*)(Ws + (nt*32+m)*40 + ks*16 + hi*8);
        accO[nt] = MFMA32(a, b, accO[nt]);
      }
    }
    __syncthreads();                       // S4: Ss/W2c consumed
  }

  // epilogue: reload token/gate, scale, transpose via As, coalesced (RMW) store
  if(t<128){
    int pos = row0+t;
    bool v = pos<rend;
    ((float*)Ss)[t]   = v ? bgt[boff+pos]  : 0.f;
    ((int*)Ss)[128+t] = v ? btok[boff+pos] : -1;
  }
  __syncthreads();
  float b2v[4];
  #pragma unroll
  for(int nt=0;nt<4;nt++) b2v[nt] = b2g[e*128 + nt*32 + m];
  #pragma unroll
  for(int reg=0; reg<16; reg++){
    int rl = (reg&3) + 8*(reg>>2) + 4*hi;
    int row = rb + rl;
    float gt = ((float*)Ss)[row];
    int key = row & 15;
    #pragma unroll
    for(int nt=0;nt<4;nt++){
      int d = nt*32 + m;
      float v = (accO[nt][reg] + b2v[nt]) * gt;
      As[row*128 + (((d>>3) ^ key)<<3) + (d&7)] = f2bf(v);
    }
  }
  __syncthreads();
  {
    int lr = t>>1, half = t&1;
    int token = ((int*)Ss)[128+lr];
    if(token>=0){
      u16* dst = outg + (size_t)token*128 + half*64;
      #pragma unroll
      for(int i=0;i<8;i++){
        int g = half*8 + i;
        uint4 v = *(const uint4*)(As + lr*128 + ((g ^ (lr&15))<<3));
        if(slot==1){
          uint4 o = *(const uint4*)(dst + i*8);
          v.x = bfadd2(v.x, o.x); v.y = bfadd2(v.y, o.y);
          v.z = bfadd2(v.z, o.z); v.w = bfadd2(v.w, o.w);
        }
        *(uint4*)(dst + i*8) = v;
      }
    }
  }
}

// head GEMM: A = outg (k' = p*128+d natural order), B = WhT2[o][k'].
// wave owns 16 rows, 8-way K-split, no LDS, plain stores to dec8.
__global__ __launch_bounds__(256) void k_head(const u16* __restrict__ Aout,
    const u16* __restrict__ WhT2, float* __restrict__ dec8){
  int bid = blockIdx.x;                 // 81 mtiles x 8 ksegs
  int mb = bid>>3, kseg = bid&7;
  int t = threadIdx.x, wid = t>>6, lane = t&63;
  int quad = lane>>4, li = lane&15;
  int r0 = mb*64 + wid*16;
  int rowA = r0 + li; if(rowA >= NRW) rowA = NRW-1;
  const u16* aptr = Aout + (size_t)rowA*DP_ + kseg*1024 + quad*8;
  const u16* bptr = WhT2 + (size_t)li*DP_  + kseg*1024 + quad*8;
  f32x4 acc[6];
  #pragma unroll
  for(int j=0;j<6;j++) acc[j]=(f32x4){0,0,0,0};
  #pragma unroll 4
  for(int ks=0;ks<32;ks++){
    bf16x8 af = *(const bf16x8*)(aptr + ks*32);
    #pragma unroll
    for(int nt=0;nt<6;nt++){
      bf16x8 bw = *(const bf16x8*)(bptr + (size_t)nt*16*DP_ + ks*32);
      acc[nt] = MFMA16(af, bw, acc[nt]);
    }
  }
  float* dst = dec8 + (size_t)kseg*NRW*96;
  #pragma unroll
  for(int nt=0;nt<6;nt++)
    #pragma unroll
    for(int rg=0;rg<4;rg++){
      int mm = r0 + quad*4 + rg;
      if(mm < NRW) dst[(size_t)mm*96 + nt*16 + li] = acc[nt][rg];
    }
}

// sum 8 k-segments + transpose + bias + denorm
__global__ void k_final(const float* __restrict__ dec8, const float* __restrict__ bhead,
    const float* __restrict__ stdp, const float* __restrict__ meanp, float* __restrict__ outp){
  __shared__ float s[64*97];
  int b = blockIdx.y, v0 = blockIdx.x*64;
  int t = threadIdx.x;
  for(int i=t;i<6144;i+=256){
    int vi = i/96, o = i - vi*96;
    int v = v0+vi;
    float acc = 0.f;
    if(v<NV_){
      size_t base = (size_t)(b*NV_+v)*96 + o;
      #pragma unroll
      for(int ks=0;ks<8;ks++) acc += dec8[(size_t)ks*NRW*96 + base];
    }
    s[vi*97+o] = acc;
  }
  __syncthreads();
  for(int i=t;i<6144;i+=256){
    int o = i>>6, vi = i&63;
    int v = v0+vi;
    if(v<NV_){
      int r = b*NV_+v;
      outp[((size_t)b*96 + o)*NV_ + v] = (s[vi*97+o] + bhead[o])*stdp[r] + meanp[r];
    }
  }
}

// ============ launcher ============
extern "C" void kernel_launch(void* const* d_in, const int* in_sizes, int n_in,
                              void* d_out, int out_size, void* d_ws, size_t ws_size,
                              hipStream_t stream){
  const float* x_enc = (const float*)d_in[0];
  const float* W_val = (const float*)d_in[4];
  const float* W_g   = (const float*)d_in[5];
  const float* W1    = (const float*)d_in[6];
  const float* b1    = (const float*)d_in[7];
  const float* W2    = (const float*)d_in[8];
  const float* b2    = (const float*)d_in[9];
  const float* W_head= (const float*)d_in[10];
  const float* b_head= (const float*)d_in[11];
  float* outp = (float*)d_out;
  char* ws = (char*)d_ws;

  float* meanp = (float*)(ws+OFF_MEAN);
  float* rstdp = (float*)(ws+OFF_RSTD);
  float* stdp  = (float*)(ws+OFF_STD);
  float* xT    = (float*)(ws+OFF_XT);
  float* pe    = (float*)(ws+OFF_PE);
  u16*   W1T   = (u16*)(ws+OFF_W1T);
  u16*   W2T   = (u16*)(ws+OFF_W2T);
  u16*   WhT2  = (u16*)(ws+OFF_WHT);
  u16*   tglob = (u16*)(ws+OFF_T);
  float* dec8  = (float*)(ws+OFF_T);    // aliases tglob (dead after expert gather)
  int*   topip = (int*)(ws+OFF_TOPI);
  float2* gatep= (float2*)(ws+OFF_GATE);
  int*   ci    = (int*)(ws+OFF_CNTR+128);
  int*   btok  = (int*)(ws+OFF_BTOK);
  float* bgt   = (float*)(ws+OFF_BGT);
  u16*   outg  = (u16*)(ws+OFF_OUT);
  double* meand= (double*)(ws+OFF_MEAND);
  double* rstdd= (double*)(ws+OFF_RSTDD);
  double* Wvg  = (double*)(ws+OFF_WVG);
  double* peg  = (double*)(ws+OFF_PEG);
  float* pg    = (float*)(ws+OFF_PG);
  int*   pib   = (int*)(ws+OFF_PI);

  hipMemsetAsync(ws+OFF_CNTR, 0, 1024, stream);

  k_xt<<<dim3(11,16,B_), dim3(32,8), 0, stream>>>(x_enc, xT);
  k_stats<<<NRW, 256, 0, stream>>>(xT, meanp, rstdp, stdp, meand, rstdd);
  k_prep<<<1, 256, 0, stream>>>(W_val, W_g, pe, Wvg, peg);
  k_wt<<<dim3(16,4,E_), dim3(32,8), 0, stream>>>(W1, W1T, 128, 512);
  k_wt<<<dim3(4,16,E_), dim3(32,8), 0, stream>>>(W2, W2T, 512, 128);
  k_wh<<<dim3(4,3,64), dim3(32,8), 0, stream>>>(W_head, WhT2);
  k_embed<<<NRW, 256, 0, stream>>>(xT, meanp, rstdp, W_val, pe, tglob);
  k_gate<<<NRW, 256, 0, stream>>>(xT, meand, rstdd, Wvg, peg, topip, gatep, pg, pib);
  k_aux<<<1, 256, 0, stream>>>(pg, pib, ci, outp);
  k_scatter<<<NTOK/256, 256, 0, stream>>>(topip, gatep, ci, btok, bgt);
  k_expert<<<2576, 256, 0, stream>>>(tglob, W1T, W2T, b1, b2, ci, btok, bgt, outg, 0);
  k_expert<<<2576, 256, 0, stream>>>(tglob, W1T, W2T, b1, b2, ci, btok, bgt, outg, 1);
  k_head<<<648, 256, 0, stream>>>(outg, WhT2, dec8);
  k_final<<<dim3(6,B_), 256, 0, stream>>>(dec8, b_head, stdp, meanp, outp);
}

// Round 9
// 651.971 us; speedup vs baseline: 3.0546x; 1.1309x over previous
//
#include <hip/hip_runtime.h>
#include <hip/hip_bf16.h>

typedef unsigned short u16;
typedef unsigned int   u32;
typedef unsigned long long u64;
typedef __attribute__((ext_vector_type(8))) short bf16x8;
typedef __attribute__((ext_vector_type(4))) float f32x4;
typedef __attribute__((ext_vector_type(16))) float f32x16;

#define MFMA16(a,b,c) __builtin_amdgcn_mfma_f32_16x16x32_bf16(a,b,c,0,0,0)
#define MFMA32(a,b,c) __builtin_amdgcn_mfma_f32_32x32x16_bf16(a,b,c,0,0,0)

// ---- problem dims ----
#define NV_   321
#define B_    16
#define L_    512
#define D_    128
#define P_    64
#define E_    8
#define H_    512
#define NRW   5136        // B*NV
#define NTOK  328704      // NRW*P
#define DP_   8192        // D*P
#define NBUCK 329728      // NTOK + 8*128 padding

static __device__ __forceinline__ u16 f2bf(float f){
  __hip_bfloat16 h = __float2bfloat16(f);
  return *reinterpret_cast<u16*>(&h);
}

// sigma-form tanh-GELU: x*sigma(1.5958x(1+0.044715x^2)); exp2 maps to v_exp_f32
static __device__ __forceinline__ float gelu_f(float x){
  float x2 = x*x;
  float p  = __builtin_fmaf(-0.1029433f, x2, -2.3022083f);
  float a  = x*p;
  float en = exp2f(a);
  float r  = __builtin_amdgcn_rcpf(1.0f + en);
  return x*r;
}

static __device__ __forceinline__ u32 bfadd2(u32 a, u32 b){
  float lo = __uint_as_float(a<<16)           + __uint_as_float(b<<16);
  float hi = __uint_as_float(a&0xffff0000u)   + __uint_as_float(b&0xffff0000u);
  return (u32)f2bf(lo) | ((u32)f2bf(hi)<<16);
}

// ============ workspace layout (bytes) — end ~193 MB (budget 256 MiB) ============
static constexpr size_t alup(size_t x){ return (x + 255) & ~(size_t)255; }
static constexpr size_t OFF_MEAN = 0;
static constexpr size_t OFF_RSTD = OFF_MEAN + alup((size_t)NRW*4);
static constexpr size_t OFF_STD  = OFF_RSTD + alup((size_t)NRW*4);
static constexpr size_t OFF_XT   = OFF_STD  + alup((size_t)NRW*4);
static constexpr size_t OFF_PE   = OFF_XT   + alup((size_t)NRW*L_*4);
static constexpr size_t OFF_W1T  = OFF_PE   + alup((size_t)P_*D_*4);
static constexpr size_t OFF_W2T  = OFF_W1T  + alup((size_t)E_*H_*D_*2);
static constexpr size_t OFF_WHT  = OFF_W2T  + alup((size_t)E_*D_*H_*2);
static constexpr size_t OFF_T    = OFF_WHT  + alup((size_t)96*DP_*2);      // tokens bf16; later ALIASED as dec8
static constexpr size_t OFF_TOPI = OFF_T    + alup((size_t)NTOK*D_*2);
static constexpr size_t OFF_GATE = OFF_TOPI + alup((size_t)NTOK*4);
static constexpr size_t OFF_CNTR = OFF_GATE + alup((size_t)NTOK*8);
static constexpr size_t OFF_BTOK = OFF_CNTR + alup((size_t)1024);
static constexpr size_t OFF_BGT  = OFF_BTOK + alup((size_t)2*NBUCK*4);
static constexpr size_t OFF_OUT  = OFF_BGT  + alup((size_t)2*NBUCK*4);     // combined token outputs bf16 [token][d]
static constexpr size_t OFF_MEAND= OFF_OUT  + alup((size_t)NTOK*D_*2);
static constexpr size_t OFF_RSTDD= OFF_MEAND+ alup((size_t)NRW*8);
static constexpr size_t OFF_WVG  = OFF_RSTDD+ alup((size_t)NRW*8);
static constexpr size_t OFF_PEG  = OFF_WVG  + alup((size_t)16*8*8);
static constexpr size_t OFF_PG   = OFF_PEG  + alup((size_t)P_*E_*8);
static constexpr size_t OFF_PI   = OFF_PG   + alup((size_t)NRW*12*4);

// ci ints at OFF_CNTR+128: [16..23]=cur1 [24..31]=cur2
// [32..40]=start1 [41..49]=start2 [50..58]=bstart1 [59..67]=bstart2

// ============ kernels ============

__global__ void k_xt(const float* __restrict__ x, float* __restrict__ xT){
  __shared__ float tile[32][33];
  int b = blockIdx.z;
  int v0 = blockIdx.x*32, l0 = blockIdx.y*32;
  int tx = threadIdx.x, ty = threadIdx.y;
  for(int i=ty;i<32;i+=8){
    int l = l0+i, v = v0+tx;
    tile[i][tx] = (v<NV_) ? x[((size_t)b*L_ + l)*NV_ + v] : 0.f;
  }
  __syncthreads();
  for(int i=ty;i<32;i+=8){
    int v = v0+i, l = l0+tx;
    if(v<NV_) xT[((size_t)(b*NV_+v))*L_ + l] = tile[tx][i];
  }
}

__global__ void k_stats(const float* __restrict__ xT, float* meanp, float* rstdp, float* stdp,
                        double* meand, double* rstdd){
  __shared__ double s1[256], s2[256];
  int r = blockIdx.x, t = threadIdx.x;
  double a = (double)xT[(size_t)r*L_ + t], b = (double)xT[(size_t)r*L_ + 256 + t];
  s1[t]=a+b; s2[t]=a*a+b*b;
  __syncthreads();
  for(int o=128;o>0;o>>=1){ if(t<o){ s1[t]+=s1[t+o]; s2[t]+=s2[t+o]; } __syncthreads(); }
  if(t==0){
    double m = s1[0]*(1.0/512.0);
    double var = s2[0]*(1.0/512.0) - m*m;
    double sd = sqrt(var + 1e-5);
    meanp[r]=(float)m; stdp[r]=(float)sd; rstdp[r]=(float)(1.0/sd);
    meand[r]=m; rstdd[r]=1.0/sd;
  }
}

// PE (float32 np semantics) + Wvg=W_val@W_g, peg=pe@W_g in fp64, one block
__global__ void k_prep(const float* __restrict__ Wval, const float* __restrict__ Wg,
                       float* __restrict__ pef, double* __restrict__ Wvg,
                       double* __restrict__ peg){
  int t = threadIdx.x;
  for(int i=t;i<8192;i+=256){
    int p = i>>7, d = i&127, k = d>>1;
    double div = exp(-(double)(2*k) * (9.210340371976184 /128.0)); // ln(10000)/128
    double ang = (double)p * div;
    double v = (d&1) ? cos(ang) : sin(ang);
    pef[i] = (float)v;
  }
  __syncthreads();
  if(t<128){
    int j = t>>3, e = t&7;
    double acc = 0.0;
    for(int d=0;d<128;d++) acc += (double)Wval[j*128+d] * (double)Wg[d*8+e];
    Wvg[t] = acc;
  }
  for(int q=t;q<512;q+=256){
    int p = q>>3, e = q&7;
    double acc = 0.0;
    for(int d=0;d<128;d++) acc += (double)pef[p*128+d] * (double)Wg[d*8+e];
    peg[q] = acc;
  }
}

__global__ void k_wt(const float* __restrict__ in, u16* __restrict__ outp, int R, int C){
  __shared__ float tile[32][33];
  int e = blockIdx.z;
  int c0 = blockIdx.x*32, r0 = blockIdx.y*32;
  const float* src = in + (size_t)e*R*C;
  u16* dst = outp + (size_t)e*R*C;
  int tx=threadIdx.x, ty=threadIdx.y;
  for(int i=ty;i<32;i+=8){
    int r=r0+i, c=c0+tx;
    tile[i][tx] = (r<R && c<C) ? src[(size_t)r*C+c] : 0.f;
  }
  __syncthreads();
  for(int i=ty;i<32;i+=8){
    int c=c0+i, r=r0+tx;
    if(c<C && r<R) dst[(size_t)c*R + r] = f2bf(tile[tx][i]);
  }
}

// permuted head-weight transpose: WhT2[o][p*128+d] = W_head[(d*64+p)*96 + o]
__global__ void k_wh(const float* __restrict__ Wh, u16* __restrict__ WhT2){
  __shared__ float tile[32][33];
  int d0 = blockIdx.x*32, o0 = blockIdx.y*32, p = blockIdx.z;
  int tx = threadIdx.x, ty = threadIdx.y;
  for(int i=ty;i<32;i+=8){
    int r = (d0+i)*64 + p;
    tile[i][tx] = Wh[(size_t)r*96 + o0 + tx];
  }
  __syncthreads();
  for(int i=ty;i<32;i+=8){
    int o = o0+i;
    WhT2[(size_t)o*DP_ + p*128 + d0 + tx] = f2bf(tile[tx][i]);
  }
}

__global__ __launch_bounds__(256) void k_embed(
    const float* __restrict__ xT, const float* __restrict__ meanp, const float* __restrict__ rstdp,
    const float* __restrict__ Wval, const float* __restrict__ pe,
    u16* __restrict__ tglob)
{
  __shared__ __align__(16) float xn[520];
  int r = blockIdx.x, t = threadIdx.x;
  float mean = meanp[r], rstd = rstdp[r];
  float v0 = (xT[(size_t)r*L_ + t]       - mean)*rstd;
  float v1 = (xT[(size_t)r*L_ + 256 + t] - mean)*rstd;
  xn[t] = v0; xn[t+256] = v1;
  if(t==255){
    #pragma unroll
    for(int i=512;i<520;i++) xn[i]=v1;   // edge pad
  }
  int d0 = (t & 63)*2;
  int p0 = t >> 6;
  float2 w[16];
  #pragma unroll
  for(int j=0;j<16;j++) w[j] = *(const float2*)(Wval + j*128 + d0);
  __syncthreads();

  for(int p=p0;p<64;p+=4){
    const float4* xp = (const float4*)(xn + p*8);
    float4 x0=xp[0], x1=xp[1], x2=xp[2], x3=xp[3];
    float xv[16];
    *(float4*)(xv+0)=x0; *(float4*)(xv+4)=x1; *(float4*)(xv+8)=x2; *(float4*)(xv+12)=x3;
    float2 pw = *(const float2*)(pe + p*128 + d0);
    float a0 = pw.x, a1 = pw.y;
    #pragma unroll
    for(int j=0;j<16;j++){ a0 += xv[j]*w[j].x; a1 += xv[j]*w[j].y; }
    u32 packed = (u32)f2bf(a0) | ((u32)f2bf(a1)<<16);
    *(u32*)(tglob + ((size_t)(r*64+p)*128 + d0)) = packed;
  }
}

__global__ __launch_bounds__(256) void k_gate(
    const float* __restrict__ xT, const double* __restrict__ meand, const double* __restrict__ rstdd,
    const double* __restrict__ Wvg, const double* __restrict__ peg,
    int* __restrict__ topip, float2* __restrict__ gatep,
    float* __restrict__ pg, int* __restrict__ pib)
{
  __shared__ double xn[520];
  __shared__ double lgt[64][9];
  int r = blockIdx.x, t = threadIdx.x;
  double m = meand[r], rs = rstdd[r];
  double v0 = ((double)xT[(size_t)r*L_ + t]       - m)*rs;
  double v1 = ((double)xT[(size_t)r*L_ + 256 + t] - m)*rs;
  xn[t]=v0; xn[t+256]=v1;
  if(t==255){
    #pragma unroll
    for(int i=512;i<520;i++) xn[i]=v1;
  }
  __syncthreads();
  for(int q=t;q<512;q+=256){
    int p = q>>3, e = q&7;
    double acc = peg[q];
    #pragma unroll
    for(int j=0;j<16;j++) acc += xn[p*8+j]*Wvg[j*8+e];
    lgt[p][e] = acc;
  }
  __syncthreads();
  if(t<64){
    int token = r*64 + t;
    double l0[8];
    #pragma unroll
    for(int e=0;e<8;e++) l0[e]=lgt[t][e];
    double mx=l0[0];
    #pragma unroll
    for(int e=1;e<8;e++) mx = fmax(mx,l0[e]);
    int i1=0; double b1v=l0[0];
    #pragma unroll
    for(int e=1;e<8;e++) if(l0[e]>b1v){b1v=l0[e]; i1=e;}
    int i2=-1; double b2v=-1e300;
    #pragma unroll
    for(int e=0;e<8;e++) if(e!=i1 && l0[e]>b2v){b2v=l0[e]; i2=e;}
    float pr[8]; float sum=0.f;
    #pragma unroll
    for(int e=0;e<8;e++){ pr[e]=__expf((float)(l0[e]-mx)); sum+=pr[e]; }
    float inv = 1.f/sum;
    #pragma unroll
    for(int e=0;e<8;e++) pr[e]*=inv;
    topip[token] = i1 | (i2<<8);
    gatep[token] = make_float2(pr[i1], pr[i2]);
    float lse = (float)mx + __logf(sum);
    #pragma unroll
    for(int e=0;e<8;e++){
      float v = pr[e];
      for(int o=32;o>0;o>>=1) v += __shfl_down(v,o);
      if(t==0) pg[r*12+e] = v;
    }
    {
      float z = lse*lse;
      for(int o=32;o>0;o>>=1) z += __shfl_down(z,o);
      if(t==0) pg[r*12+8] = z;
    }
    #pragma unroll
    for(int e=0;e<8;e++){
      u64 m1 = __ballot(i1==e);
      u64 m2 = __ballot(i2==e);
      if(t==0){
        pib[r*16+e]   = (int)__popcll(m1);
        pib[r*16+8+e] = (int)__popcll(m2);
      }
    }
  }
}

__global__ __launch_bounds__(256) void k_aux(const float* __restrict__ pg, const int* __restrict__ pib,
                                             int* __restrict__ ci, float* __restrict__ dout){
  __shared__ double sd[256];
  __shared__ int si[256];
  __shared__ double totd[9];
  __shared__ int toti[16];
  int t = threadIdx.x;
  double accd[9]; int acci[16];
  #pragma unroll
  for(int c=0;c<9;c++) accd[c]=0.0;
  #pragma unroll
  for(int c=0;c<16;c++) acci[c]=0;
  for(int r=t;r<NRW;r+=256){
    #pragma unroll
    for(int c=0;c<9;c++) accd[c] += (double)pg[r*12+c];
    #pragma unroll
    for(int c=0;c<16;c++) acci[c] += pib[r*16+c];
  }
  for(int c=0;c<9;c++){
    sd[t]=accd[c]; __syncthreads();
    for(int o=128;o>0;o>>=1){ if(t<o) sd[t]+=sd[t+o]; __syncthreads(); }
    if(t==0) totd[c]=sd[0];
    __syncthreads();
  }
  for(int c=0;c<16;c++){
    si[t]=acci[c]; __syncthreads();
    for(int o=128;o>0;o>>=1){ if(t<o) si[t]+=si[t+o]; __syncthreads(); }
    if(t==0) toti[c]=si[0];
    __syncthreads();
  }
  if(t==0){
    const double invN = 1.0/(double)NTOK;
    double bal = 0.0;
    int es1=0, bs1=0, es2=0, bs2=0;
    for(int e=0;e<8;e++){
      int c1 = toti[e], c2 = toti[8+e];
      bal += (totd[e]*invN) * ((double)(c1+c2) * invN * 0.5);
      ci[32+e]=es1; ci[16+e]=es1; ci[50+e]=bs1;
      ci[41+e]=es2; ci[24+e]=es2; ci[59+e]=bs2;
      es1 += c1; bs1 += (c1+127)>>7;
      es2 += c2; bs2 += (c2+127)>>7;
    }
    ci[40]=es1; ci[58]=bs1;
    ci[49]=es2; ci[67]=bs2;
    dout[493056] = (float)(0.01*8.0*bal + 0.001*(totd[8]*invN));
  }
}

__global__ __launch_bounds__(256) void k_scatter(const int* __restrict__ topip,
    const float2* __restrict__ gatep, int* __restrict__ ci,
    int* __restrict__ btok, float* __restrict__ bgt){
  __shared__ int lc[16]; __shared__ int lb[16];
  int t = threadIdx.x;
  int token = blockIdx.x*256 + t;
  if(t<16) lc[t]=0;
  __syncthreads();
  int ti = topip[token];
  float2 g = gatep[token];
  int e1 = ti & 255, e2 = (ti>>8)&255;
  int r1 = atomicAdd(&lc[e1],1);
  int r2 = atomicAdd(&lc[8+e2],1);
  __syncthreads();
  if(t<8)            lb[t] = atomicAdd(&ci[16+t],   lc[t]);
  else if(t<16)      lb[t] = atomicAdd(&ci[24+t-8], lc[t]);
  __syncthreads();
  int p1 = lb[e1]+r1, p2 = lb[8+e2]+r2;
  btok[p1] = token;         bgt[p1] = g.x;
  btok[NBUCK+p2] = token;   bgt[NBUCK+p2] = g.y;
}

// fused per-expert FFN v6: A in registers (wave-private rows), Ss wave-private
// (no barriers), double-buffered W staging -> 1 barrier per hc. 48KB LDS, 3 blk/CU.
__global__ __launch_bounds__(256,3) void k_expert(
    const u16* __restrict__ tglob,
    const u16* __restrict__ W1T, const u16* __restrict__ W2T,
    const float* __restrict__ b1g, const float* __restrict__ b2g,
    const int* __restrict__ ci,
    const int* __restrict__ btok, const float* __restrict__ bgt,
    u16* __restrict__ outg, int slot)
{
  // Wb[i]: W1c [32][136] at 0 (4352 u16), W2c [128][40] at 4352 (5120 u16)
  __shared__ __align__(16) u16 Wb[2][9472];   // 37888 B
  __shared__ __align__(16) u16 Ss[128*40];    // 10240 B (wave-private slices)
  __shared__ float gtA[128];
  __shared__ int   tkA[128];

  int bid = blockIdx.x, t = threadIdx.x;
  int stB = 32 + slot*9, bsB = 50 + slot*9;
  int boff = slot*NBUCK;
  if(bid >= ci[bsB+8]) return;
  int e = 0;
  #pragma unroll
  for(int k2=1;k2<8;k2++) if(bid >= ci[bsB+k2]) e = k2;
  int row0 = ci[stB+e] + (bid - ci[bsB+e])*128;
  int rend = ci[stB+e+1];

  if(t<128){
    int pos = row0+t;
    bool v = pos<rend;
    gtA[t] = v ? bgt[boff+pos]  : 0.f;
    tkA[t] = v ? btok[boff+pos] : -1;
  }

  int wid = t>>6, lane = t&63;
  int m = lane&31, hi = lane>>5;
  int rb = wid*32;                 // wave owns token rows rb..rb+31 (A and Ss private)

  // ---- A gather directly to registers (MFMA fragment layout) ----
  int posA = row0 + rb + m;
  int tokA = (posA<rend) ? btok[boff+posA] : 0;
  const u16* arow = tglob + (size_t)tokA*128 + hi*8;
  bf16x8 areg[8];
  #pragma unroll
  for(int ks=0;ks<8;ks++) areg[ks] = *(const bf16x8*)(arow + ks*16);

  // staging thread roles
  int hr = t>>3, q = t&7;          // W1c: row hr (32), 16 u16 at q*16
  int dr = t>>1, q2 = t&1;         // W2c: row dr (128), 16 u16 at q2*16

  { // stage buffer 0 (hc=0)
    const u16* s1 = W1T + ((size_t)e*H_ + hr)*128 + q*16;
    u16* d1 = &Wb[0][hr*136 + q*16];
    *(uint4*)(d1)   = *(const uint4*)(s1);
    *(uint4*)(d1+8) = *(const uint4*)(s1+8);
    const u16* s2 = W2T + ((size_t)e*D_ + dr)*H_ + q2*16;
    u16* d2 = &Wb[0][4352 + dr*40 + q2*16];
    *(uint4*)(d2)   = *(const uint4*)(s2);
    *(uint4*)(d2+8) = *(const uint4*)(s2+8);
  }
  __syncthreads();

  f32x16 accO[4];
  const f32x16 z16 = {0,0,0,0,0,0,0,0,0,0,0,0,0,0,0,0};
  #pragma unroll
  for(int nt=0;nt<4;nt++) accO[nt] = z16;

  for(int hc=0;hc<16;hc++){
    const u16* W1c = &Wb[hc&1][0];
    const u16* W2c = &Wb[hc&1][4352];
    // issue next-chunk loads early (land in regs; ds_writes at iteration end)
    uint4 l0,l1,l2,l3;
    if(hc<15){
      const u16* s1 = W1T + ((size_t)e*H_ + (hc+1)*32 + hr)*128 + q*16;
      l0 = *(const uint4*)(s1); l1 = *(const uint4*)(s1+8);
      const u16* s2 = W2T + ((size_t)e*D_ + dr)*H_ + (hc+1)*32 + q2*16;
      l2 = *(const uint4*)(s2); l3 = *(const uint4*)(s2+8);
    }
    // GEMM1: S(128x32) = A(regs)@W1c
    f32x16 acc1 = z16;
    #pragma unroll
    for(int ks=0;ks<8;ks++){
      bf16x8 b = *(const bf16x8*)(W1c + m*136 + ks*16 + hi*8);
      acc1 = MFMA32(areg[ks], b, acc1);
    }
    float bv = b1g[e*H_ + hc*32 + m];
    #pragma unroll
    for(int reg=0; reg<16; reg++){
      int rl = (reg&3) + 8*(reg>>2) + 4*hi;
      Ss[(rb+rl)*40 + m] = f2bf(gelu_f(acc1[reg] + bv));
    }
    // GEMM2: accO += S@W2c (wave-private Ss; compiler lgkmcnt covers RAW)
    #pragma unroll
    for(int ks=0;ks<2;ks++){
      bf16x8 a = *(const bf16x8*)(Ss + (rb+m)*40 + ks*16 + hi*8);
      #pragma unroll
      for(int nt=0;nt<4;nt++){
        bf16x8 b = *(const bf16x8*)(W2c + (nt*32+m)*40 + ks*16 + hi*8);
        accO[nt] = MFMA32(a, b, accO[nt]);
      }
    }
    if(hc<15){
      u16* d1 = &Wb[(hc+1)&1][hr*136 + q*16];
      *(uint4*)(d1)   = l0; *(uint4*)(d1+8) = l1;
      u16* d2 = &Wb[(hc+1)&1][4352 + dr*40 + q2*16];
      *(uint4*)(d2)   = l2; *(uint4*)(d2+8) = l3;
      __syncthreads();               // the ONE barrier per hc
    }
  }

  // ---- epilogue: bias+gate, transpose via wave-private Ss in 4 d-chunks ----
  float b2v[4];
  #pragma unroll
  for(int nt=0;nt<4;nt++) b2v[nt] = b2g[e*128 + nt*32 + m];
  float gts[16];
  #pragma unroll
  for(int reg=0; reg<16; reg++){
    int rl = (reg&3) + 8*(reg>>2) + 4*hi;
    gts[reg] = gtA[rb+rl];
  }
  int lr2 = lane>>1, hf = lane&1;
  int tok2 = tkA[rb+lr2];
  u16* dstbase = outg + (size_t)((tok2<0)?0:tok2)*128 + hf*16;
  #pragma unroll
  for(int nt=0;nt<4;nt++){
    #pragma unroll
    for(int reg=0; reg<16; reg++){
      int rl = (reg&3) + 8*(reg>>2) + 4*hi;
      Ss[(rb+rl)*40 + m] = f2bf((accO[nt][reg] + b2v[nt]) * gts[reg]);
    }
    __builtin_amdgcn_s_waitcnt(0);   // drain LDS writes (cross-lane, same wave)
    if(tok2>=0){
      const u16* sp = Ss + (rb+lr2)*40 + hf*16;
      uint4 v0 = *(const uint4*)(sp);
      uint4 v1 = *(const uint4*)(sp+8);
      u16* dp = dstbase + nt*32;
      if(slot==1){
        uint4 o0 = *(const uint4*)(dp), o1 = *(const uint4*)(dp+8);
        v0.x=bfadd2(v0.x,o0.x); v0.y=bfadd2(v0.y,o0.y);
        v0.z=bfadd2(v0.z,o0.z); v0.w=bfadd2(v0.w,o0.w);
        v1.x=bfadd2(v1.x,o1.x); v1.y=bfadd2(v1.y,o1.y);
        v1.z=bfadd2(v1.z,o1.z); v1.w=bfadd2(v1.w,o1.w);
      }
      *(uint4*)(dp)   = v0;
      *(uint4*)(dp+8) = v1;
    }
    __builtin_amdgcn_s_waitcnt(0);   // reads done before next chunk overwrites
  }
}

// head GEMM: A = outg (k' = p*128+d natural order), B = WhT2[o][k'].
// wave owns 16 rows, 8-way K-split, no LDS, plain stores to dec8.
__global__ __launch_bounds__(256) void k_head(const u16* __restrict__ Aout,
    const u16* __restrict__ WhT2, float* __restrict__ dec8){
  int bid = blockIdx.x;                 // 81 mtiles x 8 ksegs
  int mb = bid>>3, kseg = bid&7;
  int t = threadIdx.x, wid = t>>6, lane = t&63;
  int quad = lane>>4, li = lane&15;
  int r0 = mb*64 + wid*16;
  int rowA = r0 + li; if(rowA >= NRW) rowA = NRW-1;
  const u16* aptr = Aout + (size_t)rowA*DP_ + kseg*1024 + quad*8;
  const u16* bptr = WhT2 + (size_t)li*DP_  + kseg*1024 + quad*8;
  f32x4 acc[6];
  #pragma unroll
  for(int j=0;j<6;j++) acc[j]=(f32x4){0,0,0,0};
  #pragma unroll 4
  for(int ks=0;ks<32;ks++){
    bf16x8 af = *(const bf16x8*)(aptr + ks*32);
    #pragma unroll
    for(int nt=0;nt<6;nt++){
      bf16x8 bw = *(const bf16x8*)(bptr + (size_t)nt*16*DP_ + ks*32);
      acc[nt] = MFMA16(af, bw, acc[nt]);
    }
  }
  float* dst = dec8 + (size_t)kseg*NRW*96;
  #pragma unroll
  for(int nt=0;nt<6;nt++)
    #pragma unroll
    for(int rg=0;rg<4;rg++){
      int mm = r0 + quad*4 + rg;
      if(mm < NRW) dst[(size_t)mm*96 + nt*16 + li] = acc[nt][rg];
    }
}

// sum 8 k-segments + transpose + bias + denorm
__global__ void k_final(const float* __restrict__ dec8, const float* __restrict__ bhead,
    const float* __restrict__ stdp, const float* __restrict__ meanp, float* __restrict__ outp){
  __shared__ float s[64*97];
  int b = blockIdx.y, v0 = blockIdx.x*64;
  int t = threadIdx.x;
  for(int i=t;i<6144;i+=256){
    int vi = i/96, o = i - vi*96;
    int v = v0+vi;
    float acc = 0.f;
    if(v<NV_){
      size_t base = (size_t)(b*NV_+v)*96 + o;
      #pragma unroll
      for(int ks=0;ks<8;ks++) acc += dec8[(size_t)ks*NRW*96 + base];
    }
    s[vi*97+o] = acc;
  }
  __syncthreads();
  for(int i=t;i<6144;i+=256){
    int o = i>>6, vi = i&63;
    int v = v0+vi;
    if(v<NV_){
      int r = b*NV_+v;
      outp[((size_t)b*96 + o)*NV_ + v] = (s[vi*97+o] + bhead[o])*stdp[r] + meanp[r];
    }
  }
}

// ============ launcher ============
extern "C" void kernel_launch(void* const* d_in, const int* in_sizes, int n_in,
                              void* d_out, int out_size, void* d_ws, size_t ws_size,
                              hipStream_t stream){
  const float* x_enc = (const float*)d_in[0];
  const float* W_val = (const float*)d_in[4];
  const float* W_g   = (const float*)d_in[5];
  const float* W1    = (const float*)d_in[6];
  const float* b1    = (const float*)d_in[7];
  const float* W2    = (const float*)d_in[8];
  const float* b2    = (const float*)d_in[9];
  const float* W_head= (const float*)d_in[10];
  const float* b_head= (const float*)d_in[11];
  float* outp = (float*)d_out;
  char* ws = (char*)d_ws;

  float* meanp = (float*)(ws+OFF_MEAN);
  float* rstdp = (float*)(ws+OFF_RSTD);
  float* stdp  = (float*)(ws+OFF_STD);
  float* xT    = (float*)(ws+OFF_XT);
  float* pe    = (float*)(ws+OFF_PE);
  u16*   W1T   = (u16*)(ws+OFF_W1T);
  u16*   W2T   = (u16*)(ws+OFF_W2T);
  u16*   WhT2  = (u16*)(ws+OFF_WHT);
  u16*   tglob = (u16*)(ws+OFF_T);
  float* dec8  = (float*)(ws+OFF_T);    // aliases tglob (dead after expert gather)
  int*   topip = (int*)(ws+OFF_TOPI);
  float2* gatep= (float2*)(ws+OFF_GATE);
  int*   ci    = (int*)(ws+OFF_CNTR+128);
  int*   btok  = (int*)(ws+OFF_BTOK);
  float* bgt   = (float*)(ws+OFF_BGT);
  u16*   outg  = (u16*)(ws+OFF_OUT);
  double* meand= (double*)(ws+OFF_MEAND);
  double* rstdd= (double*)(ws+OFF_RSTDD);
  double* Wvg  = (double*)(ws+OFF_WVG);
  double* peg  = (double*)(ws+OFF_PEG);
  float* pg    = (float*)(ws+OFF_PG);
  int*   pib   = (int*)(ws+OFF_PI);

  hipMemsetAsync(ws+OFF_CNTR, 0, 1024, stream);

  k_xt<<<dim3(11,16,B_), dim3(32,8), 0, stream>>>(x_enc, xT);
  k_stats<<<NRW, 256, 0, stream>>>(xT, meanp, rstdp, stdp, meand, rstdd);
  k_prep<<<1, 256, 0, stream>>>(W_val, W_g, pe, Wvg, peg);
  k_wt<<<dim3(16,4,E_), dim3(32,8), 0, stream>>>(W1, W1T, 128, 512);
  k_wt<<<dim3(4,16,E_), dim3(32,8), 0, stream>>>(W2, W2T, 512, 128);
  k_wh<<<dim3(4,3,64), dim3(32,8), 0, stream>>>(W_head, WhT2);
  k_embed<<<NRW, 256, 0, stream>>>(xT, meanp, rstdp, W_val, pe, tglob);
  k_gate<<<NRW, 256, 0, stream>>>(xT, meand, rstdd, Wvg, peg, topip, gatep, pg, pib);
  k_aux<<<1, 256, 0, stream>>>(pg, pib, ci, outp);
  k_scatter<<<NTOK/256, 256, 0, stream>>>(topip, gatep, ci, btok, bgt);
  k_expert<<<2576, 256, 0, stream>>>(tglob, W1T, W2T, b1, b2, ci, btok, bgt, outg, 0);
  k_expert<<<2576, 256, 0, stream>>>(tglob, W1T, W2T, b1, b2, ci, btok, bgt, outg, 1);
  k_head<<<648, 256, 0, stream>>>(outg, WhT2, dec8);
  k_final<<<dim3(6,B_), 256, 0, stream>>>(dec8, b_head, stdp, meanp, outp);
}